// Round 6
// baseline (870.017 us; speedup 1.0000x reference)
//
#include <hip/hip_runtime.h>

typedef __attribute__((ext_vector_type(8))) short short8;
typedef __attribute__((ext_vector_type(4))) float f32x4;

#define DEVFN __device__ __forceinline__

constexpr float NEGF = -4294967296.0f;              // -(1<<32)
// 1/sqrt(512) * log2(e): folded into Qp by k_proj; softmax runs in base-2.
constexpr float SCALE_LOG2E = 0.06375872f;

DEVFN unsigned short f2bf(float f) {
  unsigned int u = __float_as_uint(f);
  u += 0x7FFFu + ((u >> 16) & 1u);   // RNE (inputs finite)
  return (unsigned short)(u >> 16);
}
DEVFN float bf2f(unsigned short h) { return __uint_as_float((unsigned)h << 16); }

DEVFN float exp2v(float x) {  // raw v_exp_f32: D = 2^S0 (no log2e mul)
  float r;
  asm("v_exp_f32 %0, %1" : "=v"(r) : "v"(x));
  return r;
}

DEVFN void gl_lds16(const void* g, void* l) {
  __builtin_amdgcn_global_load_lds(
      (const __attribute__((address_space(1))) unsigned int*)g,
      (__attribute__((address_space(3))) unsigned int*)l, 16, 0, 0);
}

// 16-lane butterfly reductions on the VALU (DPP) instead of ds_swizzle (LDS pipe).
DEVFN float dpp_fmax16(float x) {
  int v;
  v = __builtin_amdgcn_update_dpp(0, __float_as_int(x), 0xB1, 0xF, 0xF, true);
  x = fmaxf(x, __int_as_float(v));
  v = __builtin_amdgcn_update_dpp(0, __float_as_int(x), 0x4E, 0xF, 0xF, true);
  x = fmaxf(x, __int_as_float(v));
  v = __builtin_amdgcn_update_dpp(0, __float_as_int(x), 0x141, 0xF, 0xF, true);
  x = fmaxf(x, __int_as_float(v));
  v = __builtin_amdgcn_update_dpp(0, __float_as_int(x), 0x140, 0xF, 0xF, true);
  x = fmaxf(x, __int_as_float(v));
  return x;
}
DEVFN float dpp_fadd16(float x) {
  int v;
  v = __builtin_amdgcn_update_dpp(0, __float_as_int(x), 0xB1, 0xF, 0xF, true);
  x += __int_as_float(v);
  v = __builtin_amdgcn_update_dpp(0, __float_as_int(x), 0x4E, 0xF, 0xF, true);
  x += __int_as_float(v);
  v = __builtin_amdgcn_update_dpp(0, __float_as_int(x), 0x141, 0xF, 0xF, true);
  x += __int_as_float(v);
  v = __builtin_amdgcn_update_dpp(0, __float_as_int(x), 0x140, 0xF, 0xF, true);
  x += __int_as_float(v);
  return x;
}

// ---------- merged detectors: block 0 = Q dtype, block 1 = mask esize ----------
__global__ void k_detect(const unsigned int* __restrict__ q, const unsigned int* __restrict__ m,
                         int* __restrict__ fflag, int* __restrict__ esize) {
  int lane = threadIdx.x;
  if (blockIdx.x == 0) {
    unsigned bad = 0;
    for (int i = 0; i < 64; i++) {
      unsigned v = q[i * 64 + lane];
      unsigned h = v & 0xFFFFu;
      unsigned e = (h >> 7) & 0xFFu;
      if (h != 0u && (e < 96u || e > 150u)) bad = 1;
    }
    unsigned long long anyb = __ballot(bad != 0);
    if (lane == 0) *fflag = (anyb == 0ULL) ? 1 : 0;
  } else {
    unsigned okd = 1, okh = 1, okb = 1;
    for (int i = 0; i < 64; i++) {
      unsigned v = m[i * 64 + lane];
      if (v > 1u && v != 0x3F800000u) okd = 0;   // int32/f32 0|1|1.0f
      unsigned h0 = v & 0xFFFFu, h1 = v >> 16;
      if ((h0 && h0 != 0x3F80u && h0 != 1u) || (h1 && h1 != 0x3F80u && h1 != 1u)) okh = 0;
      if (v & 0xFEFEFEFEu) okb = 0;
    }
    okd = (__ballot(okd == 0) == 0ULL);
    okh = (__ballot(okh == 0) == 0ULL);
    okb = (__ballot(okb == 0) == 0ULL);
    if (lane == 0) *esize = okd ? 4 : (okh ? 2 : 1);
  }
}

// ---------- fused convert-or-copy -> bf16 for Q,K,WQw,WKw,bq,bk ----------
__global__ void k_prep(const void* __restrict__ Q, unsigned short* __restrict__ Qb,
                       const void* __restrict__ K, unsigned short* __restrict__ Kb,
                       const void* __restrict__ Wq, unsigned short* __restrict__ Wqb,
                       const void* __restrict__ Wk, unsigned short* __restrict__ Wkb,
                       const void* __restrict__ bq, unsigned short* __restrict__ bqb,
                       const void* __restrict__ bk, unsigned short* __restrict__ bkb,
                       const int* __restrict__ bf16flag) {
  int blk = blockIdx.x;
  const void* src; unsigned short* dst; int base, n;
  if (blk < 2048)      { src = Q;  dst = Qb;  base = blk;        n = 8192 * 512; }
  else if (blk < 4096) { src = K;  dst = Kb;  base = blk - 2048; n = 8192 * 512; }
  else if (blk < 4224) { src = Wq; dst = Wqb; base = blk - 4096; n = 512 * 512; }
  else if (blk < 4352) { src = Wk; dst = Wkb; base = blk - 4224; n = 512 * 512; }
  else if (blk == 4352){ src = bq; dst = bqb; base = 0;          n = 512; }
  else                 { src = bk; dst = bkb; base = 0;          n = 512; }
  int i = (base * 256 + threadIdx.x) * 8;
  if (i >= n) return;
  if (*bf16flag) {
    *(uint4*)(dst + i) = *(const uint4*)((const unsigned short*)src + i);
  } else {
    const float* f = (const float*)src + i;
    float4 a = *(const float4*)f, b = *(const float4*)(f + 4);
    uint4 o;
    o.x = (unsigned)f2bf(a.x) | ((unsigned)f2bf(a.y) << 16);
    o.y = (unsigned)f2bf(a.z) | ((unsigned)f2bf(a.w) << 16);
    o.z = (unsigned)f2bf(b.x) | ((unsigned)f2bf(b.y) << 16);
    o.w = (unsigned)f2bf(b.z) | ((unsigned)f2bf(b.w) << 16);
    *(uint4*)(dst + i) = o;
  }
}

// ---------- V [8192x512] -> tiled V^T: Vt[t][d][c], tiles of 32 k-rows ----------
__global__ void k_transpose_v(const void* __restrict__ Vsrc, const int* __restrict__ bf16flag,
                              unsigned short* __restrict__ Vt) {
  __shared__ unsigned short T[64][72];
  int t = threadIdx.x;
  int rb = blockIdx.x, cb = blockIdx.y;
  int r = t >> 3, c8 = (t & 7) * 8;
  int isbf = *bf16flag;
#pragma unroll
  for (int j = 0; j < 2; j++) {
    int row = rb * 64 + j * 32 + r;
    unsigned short e[8];
    if (isbf) {
      alignas(16) unsigned short tmp[8];
      *(uint4*)tmp = *(const uint4*)((const unsigned short*)Vsrc + (size_t)row * 512 + cb * 64 + c8);
#pragma unroll
      for (int i = 0; i < 8; i++) e[i] = tmp[i];
    } else {
      const float* f = (const float*)Vsrc + (size_t)row * 512 + cb * 64 + c8;
      float4 a = *(const float4*)f, b = *(const float4*)(f + 4);
      e[0] = f2bf(a.x); e[1] = f2bf(a.y); e[2] = f2bf(a.z); e[3] = f2bf(a.w);
      e[4] = f2bf(b.x); e[5] = f2bf(b.y); e[6] = f2bf(b.z); e[7] = f2bf(b.w);
    }
#pragma unroll
    for (int i = 0; i < 8; i++) T[c8 + i][j * 32 + r] = e[i];
  }
  __syncthreads();
#pragma unroll
  for (int j = 0; j < 2; j++) {
    int d = cb * 64 + j * 32 + r;                   // V col = V^T row
    alignas(16) unsigned short o[8];
#pragma unroll
    for (int i = 0; i < 8; i++) o[i] = T[j * 32 + r][c8 + i];
    int tt = rb * 2 + (c8 >> 5);
    *(uint4*)(Vt + ((size_t)tt * 512 + d) * 32 + (c8 & 31)) = *(const uint4*)o;
  }
}

// ---------- mask -> bit-packed row-major [8192][128] uint64 ----------
DEVFN unsigned nib4(unsigned v) {
  unsigned t = v; t |= t >> 1; t |= t >> 2; t |= t >> 4; t &= 0x01010101u;
  return (t * 0x10204080u) >> 28;
}
DEVFN unsigned pair2(unsigned v) {
  unsigned t = v; t |= t >> 8; t |= t >> 4; t |= t >> 2; t |= t >> 1;
  return (t & 1u) | (((t >> 16) & 1u) << 1);
}
__global__ void k_pack(const void* __restrict__ mask, const int* __restrict__ esize,
                       unsigned long long* __restrict__ bits) {
  int wv = (blockIdx.x * blockDim.x + threadIdx.x) >> 6;  // 4096 waves
  int lane = threadIdx.x & 63;
  int sz = *esize;
  if (sz == 4) {
    const unsigned int* m = (const unsigned int*)mask;
    for (int g = wv; g < 262144; g += 4096) {
      size_t base = (size_t)g * 256 + lane;
      unsigned v0 = m[base], v1 = m[base + 64], v2 = m[base + 128], v3 = m[base + 192];
      unsigned long long b0 = __ballot(v0 != 0u);
      unsigned long long b1 = __ballot(v1 != 0u);
      unsigned long long b2 = __ballot(v2 != 0u);
      unsigned long long b3 = __ballot(v3 != 0u);
      if (lane == 0) {
        bits[g * 4 + 0] = b0; bits[g * 4 + 1] = b1;
        bits[g * 4 + 2] = b2; bits[g * 4 + 3] = b3;
      }
    }
  } else if (sz == 2) {
    const uint4* m = (const uint4*)mask;
    for (int g = wv; g < 131072; g += 4096) {
      uint4 v = m[(size_t)g * 64 + lane];
      unsigned c8 = pair2(v.x) | (pair2(v.y) << 2) | (pair2(v.z) << 4) | (pair2(v.w) << 6);
      unsigned long long x = (unsigned long long)c8 << ((lane & 7) * 8);
      x |= __shfl_xor(x, 1); x |= __shfl_xor(x, 2); x |= __shfl_xor(x, 4);
      if ((lane & 7) == 0) bits[g * 8 + (lane >> 3)] = x;
    }
  } else {
    const uint4* m = (const uint4*)mask;
    for (int g = wv; g < 65536; g += 4096) {
      uint4 v = m[(size_t)g * 64 + lane];
      unsigned c16 = nib4(v.x) | (nib4(v.y) << 4) | (nib4(v.z) << 8) | (nib4(v.w) << 12);
      unsigned long long x = (unsigned long long)c16 << ((lane & 3) * 16);
      x |= __shfl_xor(x, 1); x |= __shfl_xor(x, 2);
      if ((lane & 3) == 0) bits[g * 16 + (lane >> 2)] = x;
    }
  }
}

// ---------- fused proj GEMM (z=0: Q, z=1: K): out = (A @ W^T + bias)*sc, bf16 ----------
// z=0 (Q side) folds SCALE_LOG2E so k_attn's softmax runs in base-2 with no muls.
__global__ __launch_bounds__(256, 2) void k_proj(
    const unsigned short* __restrict__ Aq, const unsigned short* __restrict__ Wq,
    const unsigned short* __restrict__ bq, unsigned short* __restrict__ outq,
    const unsigned short* __restrict__ Ak, const unsigned short* __restrict__ Wk,
    const unsigned short* __restrict__ bk, unsigned short* __restrict__ outk) {
  const unsigned short* A = blockIdx.z ? Ak : Aq;
  const unsigned short* W = blockIdx.z ? Wk : Wq;
  const unsigned short* bias = blockIdx.z ? bk : bq;
  unsigned short* out = blockIdx.z ? outk : outq;
  float sc = blockIdx.z ? 1.0f : SCALE_LOG2E;

  __shared__ alignas(16) unsigned short As[128 * 64];
  __shared__ alignas(16) unsigned short Bs[128 * 64];
  int tid = threadIdx.x, lane = tid & 63, wave = tid >> 6;
  int wi = wave >> 1, wj = wave & 1;
  int l15 = lane & 15, l4 = lane >> 4;
  int rowbase = blockIdx.x * 128, colbase = blockIdx.y * 128;
  f32x4 acc[4][4];
#pragma unroll
  for (int i = 0; i < 4; i++)
#pragma unroll
    for (int j = 0; j < 4; j++) acc[i][j] = f32x4{0.f, 0.f, 0.f, 0.f};

  int swr = l15 & 7;
  for (int kb = 0; kb < 512; kb += 64) {
    __syncthreads();
#pragma unroll
    for (int t = 0; t < 4; t++) {
      int inst = wave * 4 + t;
      int r = inst * 8 + (lane >> 3);
      int c = ((lane & 7) ^ (r & 7)) * 8;
      gl_lds16(A + (size_t)(rowbase + r) * 512 + kb + c, &As[inst * 512]);
      gl_lds16(W + (size_t)(colbase + r) * 512 + kb + c, &Bs[inst * 512]);
    }
    __syncthreads();
#pragma unroll
    for (int t2 = 0; t2 < 2; t2++) {
      short8 a[4], b[4];
#pragma unroll
      for (int i = 0; i < 4; i++) {
        int row = wi * 64 + i * 16 + l15;
        a[i] = *(const short8*)&As[row * 64 + (((t2 * 4 + l4) ^ swr) * 8)];
      }
#pragma unroll
      for (int j = 0; j < 4; j++) {
        int row = wj * 64 + j * 16 + l15;
        b[j] = *(const short8*)&Bs[row * 64 + (((t2 * 4 + l4) ^ swr) * 8)];
      }
#pragma unroll
      for (int i = 0; i < 4; i++)
#pragma unroll
        for (int j = 0; j < 4; j++)
          acc[i][j] = __builtin_amdgcn_mfma_f32_16x16x32_bf16(a[i], b[j], acc[i][j], 0, 0, 0);
    }
  }
#pragma unroll
  for (int j = 0; j < 4; j++) {
    int col = colbase + wj * 64 + j * 16 + l15;
    float bj = bf2f(bias[col]);
#pragma unroll
    for (int i = 0; i < 4; i++) {
      int row0 = rowbase + wi * 64 + i * 16 + l4 * 4;
#pragma unroll
      for (int r = 0; r < 4; r++)
        out[(size_t)(row0 + r) * 512 + col] = f2bf((acc[i][j][r] + bj) * sc);
    }
  }
}

// ---------- flash attention: BM=128 (8 waves), BN=32, split-K=8 ----------
// v7 = v6's counted-vmcnt single-barrier pipeline + intra-wave phase fusion:
//   * order: masks -> K(it+1) issue -> QK^T(it) -> mask-apply -> fence ->
//     fused {PV(it-1) MFMA quads interleaved with softmax(it) pieces} ->
//     P2 write -> V(it) issue -> vmcnt(4)+lgkm(0) barrier.
//     In-order waves now issue softmax VALU while PV MFMAs occupy the matrix
//     pipe (v6 paid these phases serially).
//   * base-2 softmax: SCALE*log2e folded into Qp (k_proj); exp = raw v_exp_f32.
//   * li kept as per-lane partials; single DPP reduce in epilogue.
// FIFO: V(it-1) older than masks(it) -> compiler's mask wait (vmcnt<=4)
// guarantees VB resident before the fence; barrier vmcnt(4) retires K only,
// V(it) flies across. LDS ~113KB, 1 lockstep block/CU (v4/v5: drifting
// blocks thrash L2 -> FETCH 1GB; keep 67MB).
__global__ __launch_bounds__(512, 2) void k_attn(
    const unsigned short* __restrict__ Qp, const unsigned short* __restrict__ Kp,
    const unsigned short* __restrict__ Vt, const unsigned long long* __restrict__ mbits,
    unsigned short* __restrict__ Opart, float* __restrict__ mpart, float* __restrict__ lpart) {
  __shared__ alignas(16) unsigned short KB[2][16384];   // 2 x 32 k-rows x 512 (col-swizzled)
  __shared__ alignas(16) unsigned short VB[16384];      // 512 d-rows x 32 (chunk-swizzled)
  __shared__ alignas(16) unsigned short P2[2][4][128][8];  // 2 x [koct][q-row][8]
  __shared__ alignas(16) float alds[2][128];            // per-row rescale factor
  __shared__ alignas(16) int nfl[2][8];                 // per-wave rescale flags
  int tid = threadIdx.x, lane = tid & 63, wave = tid >> 6;
  int l15 = lane & 15, l4 = lane >> 4;
  int b = blockIdx.x;
  int split = b & 7;
  int qb = (b >> 3) * 128;

  short8 qf[16];  // persistent Q fragments: wave's 16 rows x 512
  {
    int row = qb + wave * 16 + l15;
#pragma unroll
    for (int t = 0; t < 16; t++)
      qf[t] = *(const short8*)(Qp + (size_t)row * 512 + t * 32 + l4 * 8);
  }
  f32x4 o[8][4];  // all 128 rows x wave's 64 d-cols
#pragma unroll
  for (int i = 0; i < 8; i++)
#pragma unroll
    for (int j = 0; j < 4; j++) o[i][j] = f32x4{0.f, 0.f, 0.f, 0.f};
  float mi[4] = {NEGF, NEGF, NEGF, NEGF};
  float li_l[4] = {0.f, 0.f, 0.f, 0.f};   // per-lane partial row sums

  int swK = l15 | ((l15 & 3) << 4);   // K read swizzle (matches deposit swz(row))
  const unsigned int* mb32 = (const unsigned int*)mbits;

#define STAGE_K(TV, BUF)                                                         \
  {                                                                              \
    _Pragma("unroll") for (int t = 0; t < 4; t++) {                              \
      int r = wave * 4 + t;                                                      \
      int swz = (r & 15) | ((r & 3) << 4);                                       \
      gl_lds16(Kp + (size_t)((TV) * 32 + r) * 512 + ((lane ^ swz) * 8),          \
               &KB[BUF][r * 512]);                                               \
    }                                                                            \
  }
#define STAGE_V(TV)                                                              \
  {                                                                              \
    _Pragma("unroll") for (int t = 0; t < 4; t++) {                              \
      int inst = wave * 4 + t;                                                   \
      int d = inst * 16 + (lane >> 2);                                           \
      int cg = (lane & 3) ^ ((d >> 2) & 3);                                      \
      gl_lds16(Vt + (size_t)(TV) * 16384 + d * 32 + cg * 8, &VB[inst * 512]);    \
    }                                                                            \
  }
#define LOAD_MASKS(IT)                                                           \
  _Pragma("unroll") for (int r = 0; r < 4; r++)                                  \
    mw[r] = mb32[((size_t)(qb + wave * 16 + l4 * 4 + r) * 128 + split * 16 +     \
                  ((IT) >> 1)) * 2 + ((IT) & 1)];
#define QKT(BUF)                                                                 \
  {                                                                              \
    _Pragma("unroll") for (int c = 0; c < 2; c++) sacc[c] = f32x4{0.f,0.f,0.f,0.f}; \
    __builtin_amdgcn_s_setprio(1);                                               \
    _Pragma("unroll") for (int t2 = 0; t2 < 16; t2++) {                          \
      short8 a = qf[t2];                                                         \
      _Pragma("unroll") for (int c = 0; c < 2; c++) {                            \
        int row = c * 16 + l15;                                                  \
        short8 bb = *(const short8*)&KB[BUF][row * 512 + (((t2 * 4 + l4) ^ swK) * 8)]; \
        sacc[c] = __builtin_amdgcn_mfma_f32_16x16x32_bf16(a, bb, sacc[c], 0, 0, 0); \
      }                                                                          \
    }                                                                            \
    __builtin_amdgcn_s_setprio(0);                                               \
  }
#define MASK_APPLY()                                                             \
  _Pragma("unroll") for (int c = 0; c < 2; c++)                                  \
    _Pragma("unroll") for (int r = 0; r < 4; r++) {                              \
      bool msk = (mw[r] >> (c * 16 + l15)) & 1u;                                 \
      sacc[c][r] = msk ? NEGF : sacc[c][r];                                      \
    }

  // prologue: stage K(0) -> KB[0], drain, sync
  STAGE_K(split * 32, 0);
  __builtin_amdgcn_s_waitcnt(0x0F70);  // vmcnt(0)
  __builtin_amdgcn_s_barrier();

  // ---- iteration 0: QK^T + softmax only (no PV) ----
  {
    const int tv = split * 32;
    unsigned mw[4];
    LOAD_MASKS(0);
    STAGE_K(tv + 1, 1);
    f32x4 sacc[2];
    QKT(0);
    MASK_APPLY();
    float al4[4];
    bool need = false;
#pragma unroll
    for (int r = 0; r < 4; r++) {
      float t = dpp_fmax16(fmaxf(sacc[0][r], sacc[1][r]));
      al4[r] = t;
      need |= (t > mi[r] + 11.5f);
    }
    unsigned long long blt = __ballot(need);
    if (lane == 0) nfl[0][wave] = (blt != 0ULL) ? 1 : 0;
    if (blt) {
#pragma unroll
      for (int r = 0; r < 4; r++) {
        float mn = fmaxf(mi[r], al4[r]);
        float a = exp2v(mi[r] - mn);
        li_l[r] *= a;
        mi[r] = mn;
        al4[r] = a;
      }
    } else {
#pragma unroll
      for (int r = 0; r < 4; r++) al4[r] = 1.0f;
    }
    if (l15 == 0) *(f32x4*)&alds[0][wave * 16 + l4 * 4] = f32x4{al4[0], al4[1], al4[2], al4[3]};
#pragma unroll
    for (int r = 0; r < 4; r++) {
      sacc[0][r] = exp2v(sacc[0][r] - mi[r]);
      sacc[1][r] = exp2v(sacc[1][r] - mi[r]);
      li_l[r] += sacc[0][r] + sacc[1][r];
    }
#pragma unroll
    for (int r = 0; r < 4; r++) {
      int prow = wave * 16 + l4 * 4 + r;
#pragma unroll
      for (int c = 0; c < 2; c++)
        P2[0][c * 2 + (l15 >> 3)][prow][l15 & 7] = f2bf(sacc[c][r]);
    }
    STAGE_V(tv);
    __builtin_amdgcn_s_waitcnt(0x0074);  // vmcnt(4) lgkmcnt(0): K(1) landed, V(0) flies
    __builtin_amdgcn_s_barrier();
  }

  // ---- main loop: fused PV(it-1) + softmax(it) ----
  for (int it = 1; it < 32; ++it) {
    const int cur = it & 1, prv = cur ^ 1;
    const int tv = split * 32 + it;

    unsigned mw[4];
    LOAD_MASKS(it);
    STAGE_K((it < 31) ? tv + 1 : tv, prv);

    f32x4 sacc[2];
    QKT(cur);
    MASK_APPLY();   // compiler waits vmcnt<=4 here: retires V(it-1)+masks, K flies

    __builtin_amdgcn_s_waitcnt(0x0F78);  // vmcnt(8) belt-and-braces for VB
    __builtin_amdgcn_sched_barrier(0);

    // deferred o-rescale (rare after warmup)
    {
      const int4* n4 = (const int4*)&nfl[prv][0];
      int4 na = n4[0], nb4 = n4[1];
      if (na.x | na.y | na.z | na.w | nb4.x | nb4.y | nb4.z | nb4.w) {
#pragma unroll
        for (int rf = 0; rf < 8; rf++) {
          f32x4 av = *(const f32x4*)&alds[prv][rf * 16 + l4 * 4];
#pragma unroll
          for (int df = 0; df < 4; df++)
#pragma unroll
            for (int j = 0; j < 4; j++) o[rf][df][j] *= av[j];
        }
      }
    }
    short8 vf[4];
#pragma unroll
    for (int df = 0; df < 4; df++) {
      int d = wave * 64 + df * 16 + l15;
      vf[df] = *(const short8*)&VB[d * 32 + ((l4 ^ ((l15 >> 2) & 3)) * 8)];
    }

    float al4[4];
    bool need = false;
    unsigned long long blt = 0;
    __builtin_amdgcn_s_setprio(1);
#pragma unroll
    for (int rf = 0; rf < 8; rf++) {
      short8 pa = *(const short8*)&P2[prv][l4][rf * 16 + l15][0];
#pragma unroll
      for (int df = 0; df < 4; df++)
        o[rf][df] = __builtin_amdgcn_mfma_f32_16x16x32_bf16(pa, vf[df], o[rf][df], 0, 0, 0);
      // softmax piece rf: VALU issues while PV MFMAs occupy the matrix pipe
      if (rf < 4) {
        const int r = rf;
        float t = dpp_fmax16(fmaxf(sacc[0][r], sacc[1][r]));
        al4[r] = t;
        need |= (t > mi[r] + 11.5f);
      } else if (rf == 4) {
        blt = __ballot(need);
        if (lane == 0) nfl[cur][wave] = (blt != 0ULL) ? 1 : 0;
        if (blt) {
#pragma unroll
          for (int r = 0; r < 4; r++) {
            float mn = fmaxf(mi[r], al4[r]);
            float a = exp2v(mi[r] - mn);
            li_l[r] *= a;
            mi[r] = mn;
            al4[r] = a;
          }
        } else {
#pragma unroll
          for (int r = 0; r < 4; r++) al4[r] = 1.0f;
        }
        if (l15 == 0) *(f32x4*)&alds[cur][wave * 16 + l4 * 4] = f32x4{al4[0], al4[1], al4[2], al4[3]};
      } else if (rf == 5) {
#pragma unroll
        for (int r = 0; r < 2; r++) {
          sacc[0][r] = exp2v(sacc[0][r] - mi[r]);
          sacc[1][r] = exp2v(sacc[1][r] - mi[r]);
          li_l[r] += sacc[0][r] + sacc[1][r];
        }
      } else if (rf == 6) {
#pragma unroll
        for (int r = 2; r < 4; r++) {
          sacc[0][r] = exp2v(sacc[0][r] - mi[r]);
          sacc[1][r] = exp2v(sacc[1][r] - mi[r]);
          li_l[r] += sacc[0][r] + sacc[1][r];
        }
      } else {
#pragma unroll
        for (int r = 0; r < 4; r++) {
          int prow = wave * 16 + l4 * 4 + r;
#pragma unroll
          for (int c = 0; c < 2; c++)
            P2[cur][c * 2 + (l15 >> 3)][prow][l15 & 7] = f2bf(sacc[c][r]);
        }
      }
    }
    __builtin_amdgcn_s_setprio(0);

    STAGE_V(tv);
    __builtin_amdgcn_s_waitcnt(0x0074);  // vmcnt(4) lgkmcnt(0): K(it+1) landed, V(it) flies
    __builtin_amdgcn_s_barrier();
  }

  // ---- epilogue PV(31): buffers [1] ----
  __builtin_amdgcn_s_waitcnt(0x0F70);  // vmcnt(0): V(31) landed
  __builtin_amdgcn_sched_barrier(0);
  {
    const int4* n4 = (const int4*)&nfl[1][0];
    int4 na = n4[0], nb4 = n4[1];
    if (na.x | na.y | na.z | na.w | nb4.x | nb4.y | nb4.z | nb4.w) {
#pragma unroll
      for (int rf = 0; rf < 8; rf++) {
        f32x4 av = *(const f32x4*)&alds[1][rf * 16 + l4 * 4];
#pragma unroll
        for (int df = 0; df < 4; df++)
#pragma unroll
          for (int j = 0; j < 4; j++) o[rf][df][j] *= av[j];
      }
    }
    short8 vf[4];
#pragma unroll
    for (int df = 0; df < 4; df++) {
      int d = wave * 64 + df * 16 + l15;
      vf[df] = *(const short8*)&VB[d * 32 + ((l4 ^ ((l15 >> 2) & 3)) * 8)];
    }
#pragma unroll
    for (int rf = 0; rf < 8; rf++) {
      short8 pa = *(const short8*)&P2[1][l4][rf * 16 + l15][0];
#pragma unroll
      for (int df = 0; df < 4; df++)
        o[rf][df] = __builtin_amdgcn_mfma_f32_16x16x32_bf16(pa, vf[df], o[rf][df], 0, 0, 0);
    }
  }

  // ---- epilogue: reduce li, store m/l + fragment-layout bf16 partials ----
  float li[4];
#pragma unroll
  for (int r = 0; r < 4; r++) li[r] = dpp_fadd16(li_l[r]);
#pragma unroll
  for (int r = 0; r < 4; r++) {
    int row = qb + wave * 16 + l4 * 4 + r;
    if (l15 == 0) {
      mpart[(size_t)split * 8192 + row] = mi[r];
      lpart[(size_t)split * 8192 + row] = li[r];
    }
  }
  uint2* op2 = (uint2*)Opart;
#pragma unroll
  for (int rf = 0; rf < 8; rf++)
#pragma unroll
    for (int df = 0; df < 4; df++) {
      int f = wave * 4 + df;   // global 16-col d-frag index 0..31
      uint2 v;
      v.x = (unsigned)f2bf(o[rf][df][0]) | ((unsigned)f2bf(o[rf][df][1]) << 16);
      v.y = (unsigned)f2bf(o[rf][df][2]) | ((unsigned)f2bf(o[rf][df][3]) << 16);
      op2[(((size_t)b * 32 + f) * 8 + rf) * 64 + l4 * 16 + l15] = v;
    }
#undef STAGE_K
#undef STAGE_V
#undef LOAD_MASKS
#undef QKT
#undef MASK_APPLY
}

// ---------- combine 8 split-K partials (base-2 weights) -> f32 out ----------
__global__ void k_combine(const unsigned short* __restrict__ Opart,
                          const float* __restrict__ mpart, const float* __restrict__ lpart,
                          float* __restrict__ out) {
  int q = blockIdx.x;                 // 0..63 (128-row tile)
  int half = blockIdx.y;              // 0..1
  int tid = threadIdx.x;              // 512 threads
  int wave = tid >> 6, lane = tid & 63, l4 = (lane >> 4) & 3, l15 = lane & 15;
  int row0 = q * 128 + wave * 16 + l4 * 4;

  float w[8][4], inv[4];
#pragma unroll
  for (int r = 0; r < 4; r++) {
    float M = NEGF;
    float mv[8];
#pragma unroll
    for (int s = 0; s < 8; s++) { mv[s] = mpart[s * 8192 + row0 + r]; M = fmaxf(M, mv[s]); }
    float L = 0.f;
#pragma unroll
    for (int s = 0; s < 8; s++) {
      float ws = exp2v(mv[s] - M);    // log2-domain partial maxima
      w[s][r] = ws;
      L += ws * lpart[s * 8192 + row0 + r];
    }
    inv[r] = 1.0f / L;
  }
  const uint2* op2 = (const uint2*)Opart;
#pragma unroll
  for (int fo = 0; fo < 16; fo++) {
    int f = half * 16 + fo;
    float acc[4] = {0.f, 0.f, 0.f, 0.f};
#pragma unroll
    for (int s = 0; s < 8; s++) {
      uint2 v = op2[(((size_t)(q * 8 + s) * 32 + f) * 8 + wave) * 64 + l4 * 16 + l15];
      acc[0] += w[s][0] * bf2f((unsigned short)(v.x & 0xFFFFu));
      acc[1] += w[s][1] * bf2f((unsigned short)(v.x >> 16));
      acc[2] += w[s][2] * bf2f((unsigned short)(v.y & 0xFFFFu));
      acc[3] += w[s][3] * bf2f((unsigned short)(v.y >> 16));
    }
    int col = f * 16 + l15;
#pragma unroll
    for (int r = 0; r < 4; r++)
      out[(size_t)(row0 + r) * 512 + col] = acc[r] * inv[r];
  }
}

extern "C" void kernel_launch(void* const* d_in, const int* in_sizes, int n_in,
                              void* d_out, int out_size, void* d_ws, size_t ws_size,
                              hipStream_t stream) {
  const void* Q   = d_in[0];
  const void* K   = d_in[1];
  const void* V   = d_in[2];
  const void* WQw = d_in[3];
  const void* WQb = d_in[4];
  const void* WKw = d_in[5];
  const void* WKb = d_in[6];
  const void* mask = d_in[7];
  float* out = (float*)d_out;
  char* ws = (char*)d_ws;
  (void)in_sizes; (void)n_in; (void)out_size; (void)ws_size;

  constexpr size_t SZ_MAT = (size_t)8192 * 512 * 2;  // 8 MB bf16
  size_t off = 4096;
  unsigned short* Qb  = (unsigned short*)(ws + off); off += SZ_MAT;
  unsigned short* Kb  = (unsigned short*)(ws + off); off += SZ_MAT;
  unsigned short* Wqb = (unsigned short*)(ws + off); off += (size_t)512 * 512 * 2;
  unsigned short* Wkb = (unsigned short*)(ws + off); off += (size_t)512 * 512 * 2;
  unsigned short* bqb = (unsigned short*)(ws + off); off += 1024;
  unsigned short* bkb = (unsigned short*)(ws + off); off += 1024;
  unsigned short* Vt  = (unsigned short*)(ws + off); off += SZ_MAT;
  unsigned short* Qp  = (unsigned short*)(ws + off); off += SZ_MAT;
  unsigned short* Kp  = (unsigned short*)(ws + off); off += SZ_MAT;
  unsigned long long* mbits = (unsigned long long*)(ws + off); off += (size_t)8192 * 128 * 8;
  unsigned short* Opart = (unsigned short*)(ws + off); off += (size_t)512 * 512 * 32 * 8;  // 64 MB
  float* mpart = (float*)(ws + off); off += (size_t)8 * 8192 * 4;
  float* lpart = (float*)(ws + off); off += (size_t)8 * 8192 * 4;
  int* fflag = (int*)ws;
  int* esize = (int*)(ws + 64);

  k_detect<<<2, 64, 0, stream>>>((const unsigned int*)Q, (const unsigned int*)mask, fflag, esize);
  k_prep<<<4354, 256, 0, stream>>>(Q, Qb, K, Kb, WQw, Wqb, WKw, Wkb, WQb, bqb, WKb, bkb, fflag);
  k_transpose_v<<<dim3(128, 8), 256, 0, stream>>>(V, fflag, Vt);
  k_pack<<<1024, 256, 0, stream>>>(mask, esize, mbits);
  k_proj<<<dim3(64, 4, 2), 256, 0, stream>>>(Qb, Wqb, bqb, Qp, Kb, Wkb, bkb, Kp);
  k_attn<<<512, 512, 0, stream>>>(Qp, Kp, Vt, mbits, Opart, mpart, lpart);
  k_combine<<<dim3(64, 2), 512, 0, stream>>>(Opart, mpart, lpart, out);
}

// Round 7
// 817.754 us; speedup vs baseline: 1.0639x; 1.0639x over previous
//
#include <hip/hip_runtime.h>

typedef __attribute__((ext_vector_type(8))) short short8;
typedef __attribute__((ext_vector_type(4))) float f32x4;

#define DEVFN __device__ __forceinline__

constexpr float NEGF = -4294967296.0f;              // -(1<<32)
// 1/sqrt(512) * log2(e): folded into Qp by k_proj; softmax runs in base-2.
constexpr float SCALE_LOG2E = 0.06375872465057373f;

DEVFN unsigned short f2bf(float f) {
  unsigned int u = __float_as_uint(f);
  u += 0x7FFFu + ((u >> 16) & 1u);   // RNE (inputs finite)
  return (unsigned short)(u >> 16);
}
DEVFN float bf2f(unsigned short h) { return __uint_as_float((unsigned)h << 16); }

DEVFN float exp2v(float x) {  // raw v_exp_f32: D = 2^S0 (no log2e mul)
  float r;
  asm("v_exp_f32 %0, %1" : "=v"(r) : "v"(x));
  return r;
}

DEVFN void gl_lds16(const void* g, void* l) {
  __builtin_amdgcn_global_load_lds(
      (const __attribute__((address_space(1))) unsigned int*)g,
      (__attribute__((address_space(3))) unsigned int*)l, 16, 0, 0);
}

// 16-lane butterfly reductions on the VALU (DPP) instead of ds_swizzle (LDS pipe).
DEVFN float dpp_fmax16(float x) {
  int v;
  v = __builtin_amdgcn_update_dpp(0, __float_as_int(x), 0xB1, 0xF, 0xF, true);
  x = fmaxf(x, __int_as_float(v));
  v = __builtin_amdgcn_update_dpp(0, __float_as_int(x), 0x4E, 0xF, 0xF, true);
  x = fmaxf(x, __int_as_float(v));
  v = __builtin_amdgcn_update_dpp(0, __float_as_int(x), 0x141, 0xF, 0xF, true);
  x = fmaxf(x, __int_as_float(v));
  v = __builtin_amdgcn_update_dpp(0, __float_as_int(x), 0x140, 0xF, 0xF, true);
  x = fmaxf(x, __int_as_float(v));
  return x;
}
DEVFN float dpp_fadd16(float x) {
  int v;
  v = __builtin_amdgcn_update_dpp(0, __float_as_int(x), 0xB1, 0xF, 0xF, true);
  x += __int_as_float(v);
  v = __builtin_amdgcn_update_dpp(0, __float_as_int(x), 0x4E, 0xF, 0xF, true);
  x += __int_as_float(v);
  v = __builtin_amdgcn_update_dpp(0, __float_as_int(x), 0x141, 0xF, 0xF, true);
  x += __int_as_float(v);
  v = __builtin_amdgcn_update_dpp(0, __float_as_int(x), 0x140, 0xF, 0xF, true);
  x += __int_as_float(v);
  return x;
}

// ---------- merged detectors: block 0 = Q dtype, block 1 = mask esize ----------
__global__ void k_detect(const unsigned int* __restrict__ q, const unsigned int* __restrict__ m,
                         int* __restrict__ fflag, int* __restrict__ esize) {
  int lane = threadIdx.x;
  if (blockIdx.x == 0) {
    unsigned bad = 0;
    for (int i = 0; i < 64; i++) {
      unsigned v = q[i * 64 + lane];
      unsigned h = v & 0xFFFFu;
      unsigned e = (h >> 7) & 0xFFu;
      if (h != 0u && (e < 96u || e > 150u)) bad = 1;
    }
    unsigned long long anyb = __ballot(bad != 0);
    if (lane == 0) *fflag = (anyb == 0ULL) ? 1 : 0;
  } else {
    unsigned okd = 1, okh = 1, okb = 1;
    for (int i = 0; i < 64; i++) {
      unsigned v = m[i * 64 + lane];
      if (v > 1u && v != 0x3F800000u) okd = 0;   // int32/f32 0|1|1.0f
      unsigned h0 = v & 0xFFFFu, h1 = v >> 16;
      if ((h0 && h0 != 0x3F80u && h0 != 1u) || (h1 && h1 != 0x3F80u && h1 != 1u)) okh = 0;
      if (v & 0xFEFEFEFEu) okb = 0;
    }
    okd = (__ballot(okd == 0) == 0ULL);
    okh = (__ballot(okh == 0) == 0ULL);
    okb = (__ballot(okb == 0) == 0ULL);
    if (lane == 0) *esize = okd ? 4 : (okh ? 2 : 1);
  }
}

// ---------- fused convert-or-copy -> bf16 for Q,K,WQw,WKw,bq,bk ----------
__global__ void k_prep(const void* __restrict__ Q, unsigned short* __restrict__ Qb,
                       const void* __restrict__ K, unsigned short* __restrict__ Kb,
                       const void* __restrict__ Wq, unsigned short* __restrict__ Wqb,
                       const void* __restrict__ Wk, unsigned short* __restrict__ Wkb,
                       const void* __restrict__ bq, unsigned short* __restrict__ bqb,
                       const void* __restrict__ bk, unsigned short* __restrict__ bkb,
                       const int* __restrict__ bf16flag) {
  int blk = blockIdx.x;
  const void* src; unsigned short* dst; int base, n;
  if (blk < 2048)      { src = Q;  dst = Qb;  base = blk;        n = 8192 * 512; }
  else if (blk < 4096) { src = K;  dst = Kb;  base = blk - 2048; n = 8192 * 512; }
  else if (blk < 4224) { src = Wq; dst = Wqb; base = blk - 4096; n = 512 * 512; }
  else if (blk < 4352) { src = Wk; dst = Wkb; base = blk - 4224; n = 512 * 512; }
  else if (blk == 4352){ src = bq; dst = bqb; base = 0;          n = 512; }
  else                 { src = bk; dst = bkb; base = 0;          n = 512; }
  int i = (base * 256 + threadIdx.x) * 8;
  if (i >= n) return;
  if (*bf16flag) {
    *(uint4*)(dst + i) = *(const uint4*)((const unsigned short*)src + i);
  } else {
    const float* f = (const float*)src + i;
    float4 a = *(const float4*)f, b = *(const float4*)(f + 4);
    uint4 o;
    o.x = (unsigned)f2bf(a.x) | ((unsigned)f2bf(a.y) << 16);
    o.y = (unsigned)f2bf(a.z) | ((unsigned)f2bf(a.w) << 16);
    o.z = (unsigned)f2bf(b.x) | ((unsigned)f2bf(b.y) << 16);
    o.w = (unsigned)f2bf(b.z) | ((unsigned)f2bf(b.w) << 16);
    *(uint4*)(dst + i) = o;
  }
}

// ---------- V [8192x512] -> tiled V^T: Vt[t][d][c], tiles of 32 k-rows ----------
__global__ void k_transpose_v(const void* __restrict__ Vsrc, const int* __restrict__ bf16flag,
                              unsigned short* __restrict__ Vt) {
  __shared__ unsigned short T[64][72];
  int t = threadIdx.x;
  int rb = blockIdx.x, cb = blockIdx.y;
  int r = t >> 3, c8 = (t & 7) * 8;
  int isbf = *bf16flag;
#pragma unroll
  for (int j = 0; j < 2; j++) {
    int row = rb * 64 + j * 32 + r;
    unsigned short e[8];
    if (isbf) {
      alignas(16) unsigned short tmp[8];
      *(uint4*)tmp = *(const uint4*)((const unsigned short*)Vsrc + (size_t)row * 512 + cb * 64 + c8);
#pragma unroll
      for (int i = 0; i < 8; i++) e[i] = tmp[i];
    } else {
      const float* f = (const float*)Vsrc + (size_t)row * 512 + cb * 64 + c8;
      float4 a = *(const float4*)f, b = *(const float4*)(f + 4);
      e[0] = f2bf(a.x); e[1] = f2bf(a.y); e[2] = f2bf(a.z); e[3] = f2bf(a.w);
      e[4] = f2bf(b.x); e[5] = f2bf(b.y); e[6] = f2bf(b.z); e[7] = f2bf(b.w);
    }
#pragma unroll
    for (int i = 0; i < 8; i++) T[c8 + i][j * 32 + r] = e[i];
  }
  __syncthreads();
#pragma unroll
  for (int j = 0; j < 2; j++) {
    int d = cb * 64 + j * 32 + r;                   // V col = V^T row
    alignas(16) unsigned short o[8];
#pragma unroll
    for (int i = 0; i < 8; i++) o[i] = T[j * 32 + r][c8 + i];
    int tt = rb * 2 + (c8 >> 5);
    *(uint4*)(Vt + ((size_t)tt * 512 + d) * 32 + (c8 & 31)) = *(const uint4*)o;
  }
}

// ---------- mask -> bit-packed row-major [8192][128] uint64 ----------
DEVFN unsigned nib4(unsigned v) {
  unsigned t = v; t |= t >> 1; t |= t >> 2; t |= t >> 4; t &= 0x01010101u;
  return (t * 0x10204080u) >> 28;
}
DEVFN unsigned pair2(unsigned v) {
  unsigned t = v; t |= t >> 8; t |= t >> 4; t |= t >> 2; t |= t >> 1;
  return (t & 1u) | (((t >> 16) & 1u) << 1);
}
__global__ void k_pack(const void* __restrict__ mask, const int* __restrict__ esize,
                       unsigned long long* __restrict__ bits) {
  int wv = (blockIdx.x * blockDim.x + threadIdx.x) >> 6;  // 4096 waves
  int lane = threadIdx.x & 63;
  int sz = *esize;
  if (sz == 4) {
    const unsigned int* m = (const unsigned int*)mask;
    for (int g = wv; g < 262144; g += 4096) {
      size_t base = (size_t)g * 256 + lane;
      unsigned v0 = m[base], v1 = m[base + 64], v2 = m[base + 128], v3 = m[base + 192];
      unsigned long long b0 = __ballot(v0 != 0u);
      unsigned long long b1 = __ballot(v1 != 0u);
      unsigned long long b2 = __ballot(v2 != 0u);
      unsigned long long b3 = __ballot(v3 != 0u);
      if (lane == 0) {
        bits[g * 4 + 0] = b0; bits[g * 4 + 1] = b1;
        bits[g * 4 + 2] = b2; bits[g * 4 + 3] = b3;
      }
    }
  } else if (sz == 2) {
    const uint4* m = (const uint4*)mask;
    for (int g = wv; g < 131072; g += 4096) {
      uint4 v = m[(size_t)g * 64 + lane];
      unsigned c8 = pair2(v.x) | (pair2(v.y) << 2) | (pair2(v.z) << 4) | (pair2(v.w) << 6);
      unsigned long long x = (unsigned long long)c8 << ((lane & 7) * 8);
      x |= __shfl_xor(x, 1); x |= __shfl_xor(x, 2); x |= __shfl_xor(x, 4);
      if ((lane & 7) == 0) bits[g * 8 + (lane >> 3)] = x;
    }
  } else {
    const uint4* m = (const uint4*)mask;
    for (int g = wv; g < 65536; g += 4096) {
      uint4 v = m[(size_t)g * 64 + lane];
      unsigned c16 = nib4(v.x) | (nib4(v.y) << 4) | (nib4(v.z) << 8) | (nib4(v.w) << 12);
      unsigned long long x = (unsigned long long)c16 << ((lane & 3) * 16);
      x |= __shfl_xor(x, 1); x |= __shfl_xor(x, 2);
      if ((lane & 3) == 0) bits[g * 16 + (lane >> 2)] = x;
    }
  }
}

// ---------- fused proj GEMM (z=0: Q, z=1: K): out = (A @ W^T + bias)*sc, bf16 ----------
// z=0 (Q side) folds SCALE_LOG2E so k_attn's softmax runs in base-2 with no muls.
__global__ __launch_bounds__(256, 2) void k_proj(
    const unsigned short* __restrict__ Aq, const unsigned short* __restrict__ Wq,
    const unsigned short* __restrict__ bq, unsigned short* __restrict__ outq,
    const unsigned short* __restrict__ Ak, const unsigned short* __restrict__ Wk,
    const unsigned short* __restrict__ bk, unsigned short* __restrict__ outk) {
  const unsigned short* A = blockIdx.z ? Ak : Aq;
  const unsigned short* W = blockIdx.z ? Wk : Wq;
  const unsigned short* bias = blockIdx.z ? bk : bq;
  unsigned short* out = blockIdx.z ? outk : outq;
  float sc = blockIdx.z ? 1.0f : SCALE_LOG2E;

  __shared__ alignas(16) unsigned short As[128 * 64];
  __shared__ alignas(16) unsigned short Bs[128 * 64];
  int tid = threadIdx.x, lane = tid & 63, wave = tid >> 6;
  int wi = wave >> 1, wj = wave & 1;
  int l15 = lane & 15, l4 = lane >> 4;
  int rowbase = blockIdx.x * 128, colbase = blockIdx.y * 128;
  f32x4 acc[4][4];
#pragma unroll
  for (int i = 0; i < 4; i++)
#pragma unroll
    for (int j = 0; j < 4; j++) acc[i][j] = f32x4{0.f, 0.f, 0.f, 0.f};

  int swr = l15 & 7;
  for (int kb = 0; kb < 512; kb += 64) {
    __syncthreads();
#pragma unroll
    for (int t = 0; t < 4; t++) {
      int inst = wave * 4 + t;
      int r = inst * 8 + (lane >> 3);
      int c = ((lane & 7) ^ (r & 7)) * 8;
      gl_lds16(A + (size_t)(rowbase + r) * 512 + kb + c, &As[inst * 512]);
      gl_lds16(W + (size_t)(colbase + r) * 512 + kb + c, &Bs[inst * 512]);
    }
    __syncthreads();
#pragma unroll
    for (int t2 = 0; t2 < 2; t2++) {
      short8 a[4], b[4];
#pragma unroll
      for (int i = 0; i < 4; i++) {
        int row = wi * 64 + i * 16 + l15;
        a[i] = *(const short8*)&As[row * 64 + (((t2 * 4 + l4) ^ swr) * 8)];
      }
#pragma unroll
      for (int j = 0; j < 4; j++) {
        int row = wj * 64 + j * 16 + l15;
        b[j] = *(const short8*)&Bs[row * 64 + (((t2 * 4 + l4) ^ swr) * 8)];
      }
#pragma unroll
      for (int i = 0; i < 4; i++)
#pragma unroll
        for (int j = 0; j < 4; j++)
          acc[i][j] = __builtin_amdgcn_mfma_f32_16x16x32_bf16(a[i], b[j], acc[i][j], 0, 0, 0);
    }
  }
#pragma unroll
  for (int j = 0; j < 4; j++) {
    int col = colbase + wj * 64 + j * 16 + l15;
    float bj = bf2f(bias[col]);
#pragma unroll
    for (int i = 0; i < 4; i++) {
      int row0 = rowbase + wi * 64 + i * 16 + l4 * 4;
#pragma unroll
      for (int r = 0; r < 4; r++)
        out[(size_t)(row0 + r) * 512 + col] = f2bf((acc[i][j][r] + bj) * sc);
    }
  }
}

// ---------- flash attention: BM=128 (8 waves), BN=32, split-K=8 ----------
// v8 = v6 (best: counted-vmcnt single-barrier pipeline, 1 lockstep block/CU)
// + wave-parity phase stagger + VALU diet. v7's intra-wave fusion spilled
// (WRITE +14MB): fusion extends live ranges past the 128-VGPR cap. Stagger
// gets the same overlap with ZERO new live state: even waves run SM->PV,
// odd waves run PV->SM (both legal: PV(it-1) needs only P2[prv]+private VB,
// SM(it) needs only KB[cur]). Each SIMD then has one wave in an MFMA
// cluster while the other runs softmax VALU.
// VALU diet: base-2 softmax (scale*log2e folded into Qp; raw v_exp_f32;
// mask-apply is select-only) + deferred li (per-lane partials, one DPP
// reduce in epilogue; alpha is group-uniform so rescale commutes).
// Per-wave vmcnt FIFO (order-independent across parities):
//   V(it-1)[4, oldest] -> masks[4] -> K(it+1)[4]; vmcnt(8) retires V;
//   mask use forces vmcnt<=4 (retires masks, K flies);
//   barrier vmcnt(4) retires K; V(it) crosses the barrier in flight.
__global__ __launch_bounds__(512, 2) void k_attn(
    const unsigned short* __restrict__ Qp, const unsigned short* __restrict__ Kp,
    const unsigned short* __restrict__ Vt, const unsigned long long* __restrict__ mbits,
    unsigned short* __restrict__ Opart, float* __restrict__ mpart, float* __restrict__ lpart) {
  __shared__ alignas(16) unsigned short KB[2][16384];   // 2 x 32 k-rows x 512 (col-swizzled)
  __shared__ alignas(16) unsigned short VB[16384];      // 512 d-rows x 32 (chunk-swizzled)
  __shared__ alignas(16) unsigned short P2[2][4][128][8];  // 2 x [koct][q-row][8]
  __shared__ alignas(16) float alds[2][128];            // per-row rescale factor
  __shared__ alignas(16) int nfl[2][8];                 // per-wave rescale flags
  int tid = threadIdx.x, lane = tid & 63, wave = tid >> 6;
  int l15 = lane & 15, l4 = lane >> 4;
  int b = blockIdx.x;
  int split = b & 7;
  int qb = (b >> 3) * 128;

  short8 qf[16];  // persistent Q fragments: wave's 16 rows x 512
  {
    int row = qb + wave * 16 + l15;
#pragma unroll
    for (int t = 0; t < 16; t++)
      qf[t] = *(const short8*)(Qp + (size_t)row * 512 + t * 32 + l4 * 8);
  }
  f32x4 o[8][4];  // all 128 rows x wave's 64 d-cols
#pragma unroll
  for (int i = 0; i < 8; i++)
#pragma unroll
    for (int j = 0; j < 4; j++) o[i][j] = f32x4{0.f, 0.f, 0.f, 0.f};
  float mi[4] = {NEGF, NEGF, NEGF, NEGF};
  float li_l[4] = {0.f, 0.f, 0.f, 0.f};   // per-lane partial row sums

  int swK = l15 | ((l15 & 3) << 4);   // K read swizzle (matches deposit swz(row))
  const unsigned int* mb32 = (const unsigned int*)mbits;

#define STAGE_K(TV, BUF)                                                         \
  {                                                                              \
    _Pragma("unroll") for (int t = 0; t < 4; t++) {                              \
      int r = wave * 4 + t;                                                      \
      int swz = (r & 15) | ((r & 3) << 4);                                       \
      gl_lds16(Kp + (size_t)((TV) * 32 + r) * 512 + ((lane ^ swz) * 8),          \
               &KB[BUF][r * 512]);                                               \
    }                                                                            \
  }
#define STAGE_V(TV)                                                              \
  {                                                                              \
    _Pragma("unroll") for (int t = 0; t < 4; t++) {                              \
      int inst = wave * 4 + t;                                                   \
      int d = inst * 16 + (lane >> 2);                                           \
      int cg = (lane & 3) ^ ((d >> 2) & 3);                                      \
      gl_lds16(Vt + (size_t)(TV) * 16384 + d * 32 + cg * 8, &VB[inst * 512]);    \
    }                                                                            \
  }
#define LOAD_MASKS(IT)                                                           \
  _Pragma("unroll") for (int r = 0; r < 4; r++)                                  \
    mw[r] = mb32[((size_t)(qb + wave * 16 + l4 * 4 + r) * 128 + split * 16 +     \
                  ((IT) >> 1)) * 2 + ((IT) & 1)];
// SM_BLOCK: QK^T + mask + base-2 deferred-max softmax + P2 write (buffer CUR)
#define SM_BLOCK(CUR)                                                            \
  {                                                                              \
    f32x4 sacc[2];                                                               \
    _Pragma("unroll") for (int c = 0; c < 2; c++) sacc[c] = f32x4{0.f,0.f,0.f,0.f}; \
    __builtin_amdgcn_s_setprio(1);                                               \
    _Pragma("unroll") for (int t2 = 0; t2 < 16; t2++) {                          \
      short8 a = qf[t2];                                                         \
      _Pragma("unroll") for (int c = 0; c < 2; c++) {                            \
        int row = c * 16 + l15;                                                  \
        short8 bb = *(const short8*)&KB[CUR][row * 512 + (((t2 * 4 + l4) ^ swK) * 8)]; \
        sacc[c] = __builtin_amdgcn_mfma_f32_16x16x32_bf16(a, bb, sacc[c], 0, 0, 0); \
      }                                                                          \
    }                                                                            \
    __builtin_amdgcn_s_setprio(0);                                               \
    _Pragma("unroll") for (int c = 0; c < 2; c++)                                \
      _Pragma("unroll") for (int r = 0; r < 4; r++) {                            \
        bool msk = (mw[r] >> (c * 16 + l15)) & 1u;                               \
        sacc[c][r] = msk ? NEGF : sacc[c][r];                                    \
      }                                                                          \
    float al4[4];                                                                \
    bool need = false;                                                           \
    _Pragma("unroll") for (int r = 0; r < 4; r++) {                              \
      float t = dpp_fmax16(fmaxf(sacc[0][r], sacc[1][r]));                       \
      al4[r] = t;                                                                \
      need |= (t > mi[r] + 11.5f);                                               \
    }                                                                            \
    unsigned long long blt = __ballot(need);                                     \
    if (lane == 0) nfl[CUR][wave] = (blt != 0ULL) ? 1 : 0;                       \
    if (blt) {                                                                   \
      _Pragma("unroll") for (int r = 0; r < 4; r++) {                            \
        float mn = fmaxf(mi[r], al4[r]);                                         \
        float a = exp2v(mi[r] - mn);                                             \
        li_l[r] *= a;                                                            \
        mi[r] = mn;                                                              \
        al4[r] = a;                                                              \
      }                                                                          \
    } else {                                                                     \
      _Pragma("unroll") for (int r = 0; r < 4; r++) al4[r] = 1.0f;               \
    }                                                                            \
    if (l15 == 0) *(f32x4*)&alds[CUR][wave * 16 + l4 * 4] =                      \
        f32x4{al4[0], al4[1], al4[2], al4[3]};                                   \
    _Pragma("unroll") for (int r = 0; r < 4; r++) {                              \
      sacc[0][r] = exp2v(sacc[0][r] - mi[r]);                                    \
      sacc[1][r] = exp2v(sacc[1][r] - mi[r]);                                    \
      li_l[r] += sacc[0][r] + sacc[1][r];                                        \
    }                                                                            \
    _Pragma("unroll") for (int r = 0; r < 4; r++) {                              \
      int prow = wave * 16 + l4 * 4 + r;                                         \
      _Pragma("unroll") for (int c = 0; c < 2; c++)                              \
        P2[CUR][c * 2 + (l15 >> 3)][prow][l15 & 7] = f2bf(sacc[c][r]);           \
    }                                                                            \
  }
// PV_BLOCK: deferred o-rescale + P(prv)@V MFMAs (VB is wave-private)
#define PV_BLOCK(PRV)                                                            \
  {                                                                              \
    __builtin_amdgcn_s_waitcnt(0x0F78); /* vmcnt(8): V(it-1) landed */           \
    __builtin_amdgcn_sched_barrier(0);                                           \
    {                                                                            \
      const int4* n4 = (const int4*)&nfl[PRV][0];                                \
      int4 na = n4[0], nb4 = n4[1];                                              \
      if (na.x | na.y | na.z | na.w | nb4.x | nb4.y | nb4.z | nb4.w) {           \
        _Pragma("unroll") for (int rf = 0; rf < 8; rf++) {                       \
          f32x4 av = *(const f32x4*)&alds[PRV][rf * 16 + l4 * 4];                \
          _Pragma("unroll") for (int df = 0; df < 4; df++)                       \
            _Pragma("unroll") for (int j = 0; j < 4; j++) o[rf][df][j] *= av[j]; \
        }                                                                        \
      }                                                                          \
    }                                                                            \
    short8 vf[4];                                                                \
    _Pragma("unroll") for (int df = 0; df < 4; df++) {                           \
      int d = wave * 64 + df * 16 + l15;                                         \
      vf[df] = *(const short8*)&VB[d * 32 + ((l4 ^ ((l15 >> 2) & 3)) * 8)];      \
    }                                                                            \
    __builtin_amdgcn_s_setprio(1);                                               \
    _Pragma("unroll") for (int rf = 0; rf < 8; rf++) {                           \
      short8 pa = *(const short8*)&P2[PRV][l4][rf * 16 + l15][0];                \
      _Pragma("unroll") for (int df = 0; df < 4; df++)                           \
        o[rf][df] = __builtin_amdgcn_mfma_f32_16x16x32_bf16(pa, vf[df],          \
                                                            o[rf][df], 0, 0, 0);\
    }                                                                            \
    __builtin_amdgcn_s_setprio(0);                                               \
  }

  // prologue: stage K(0) -> KB[0], drain, sync
  STAGE_K(split * 32, 0);
  __builtin_amdgcn_s_waitcnt(0x0F70);  // vmcnt(0)
  __builtin_amdgcn_s_barrier();

  // ---- iteration 0: SM only (no PV yet) ----
  {
    const int tv = split * 32;
    unsigned mw[4];
    LOAD_MASKS(0);
    asm volatile("" ::: "memory");  // pin masks before the gl_lds issues
    STAGE_K(tv + 1, 1);
    SM_BLOCK(0);
    STAGE_V(tv);
    __builtin_amdgcn_s_waitcnt(0x0074);  // vmcnt(4) lgkmcnt(0): K(1) landed, V(0) flies
    __builtin_amdgcn_s_barrier();
  }

  // ---- main loop: parity-staggered {SM(it), PV(it-1)} ----
  const bool evenw = (wave & 1) == 0;
  for (int it = 1; it < 32; ++it) {
    const int cur = it & 1, prv = cur ^ 1;
    const int tv = split * 32 + it;

    unsigned mw[4];
    LOAD_MASKS(it);
    asm volatile("" ::: "memory");
    STAGE_K((it < 31) ? tv + 1 : tv, prv);

    if (evenw) {
      SM_BLOCK(cur);   // softmax VALU here overlaps odd waves' PV MFMAs
      PV_BLOCK(prv);
    } else {
      PV_BLOCK(prv);   // PV MFMAs here overlap even waves' softmax VALU
      SM_BLOCK(cur);
    }

    STAGE_V(tv);
    __builtin_amdgcn_s_waitcnt(0x0074);  // vmcnt(4) lgkmcnt(0): K(it+1) landed, V(it) flies
    __builtin_amdgcn_s_barrier();
  }

  // ---- epilogue PV(31): buffers [1] ----
  __builtin_amdgcn_s_waitcnt(0x0F70);  // vmcnt(0): V(31) landed
  __builtin_amdgcn_sched_barrier(0);
  PV_BLOCK(1);

  // ---- epilogue: reduce li, store m/l + fragment-layout bf16 partials ----
  float li[4];
#pragma unroll
  for (int r = 0; r < 4; r++) li[r] = dpp_fadd16(li_l[r]);
#pragma unroll
  for (int r = 0; r < 4; r++) {
    int row = qb + wave * 16 + l4 * 4 + r;
    if (l15 == 0) {
      mpart[(size_t)split * 8192 + row] = mi[r];
      lpart[(size_t)split * 8192 + row] = li[r];
    }
  }
  uint2* op2 = (uint2*)Opart;
#pragma unroll
  for (int rf = 0; rf < 8; rf++)
#pragma unroll
    for (int df = 0; df < 4; df++) {
      int f = wave * 4 + df;   // global 16-col d-frag index 0..31
      uint2 v;
      v.x = (unsigned)f2bf(o[rf][df][0]) | ((unsigned)f2bf(o[rf][df][1]) << 16);
      v.y = (unsigned)f2bf(o[rf][df][2]) | ((unsigned)f2bf(o[rf][df][3]) << 16);
      op2[(((size_t)b * 32 + f) * 8 + rf) * 64 + l4 * 16 + l15] = v;
    }
#undef STAGE_K
#undef STAGE_V
#undef LOAD_MASKS
#undef SM_BLOCK
#undef PV_BLOCK
}

// ---------- combine 8 split-K partials (base-2 weights) -> f32 out ----------
__global__ void k_combine(const unsigned short* __restrict__ Opart,
                          const float* __restrict__ mpart, const float* __restrict__ lpart,
                          float* __restrict__ out) {
  int q = blockIdx.x;                 // 0..63 (128-row tile)
  int half = blockIdx.y;              // 0..1
  int tid = threadIdx.x;              // 512 threads
  int wave = tid >> 6, lane = tid & 63, l4 = (lane >> 4) & 3, l15 = lane & 15;
  int row0 = q * 128 + wave * 16 + l4 * 4;

  float w[8][4], inv[4];
#pragma unroll
  for (int r = 0; r < 4; r++) {
    float M = NEGF;
    float mv[8];
#pragma unroll
    for (int s = 0; s < 8; s++) { mv[s] = mpart[s * 8192 + row0 + r]; M = fmaxf(M, mv[s]); }
    float L = 0.f;
#pragma unroll
    for (int s = 0; s < 8; s++) {
      float ws = exp2v(mv[s] - M);    // log2-domain partial maxima
      w[s][r] = ws;
      L += ws * lpart[s * 8192 + row0 + r];
    }
    inv[r] = 1.0f / L;
  }
  const uint2* op2 = (const uint2*)Opart;
#pragma unroll
  for (int fo = 0; fo < 16; fo++) {
    int f = half * 16 + fo;
    float acc[4] = {0.f, 0.f, 0.f, 0.f};
#pragma unroll
    for (int s = 0; s < 8; s++) {
      uint2 v = op2[(((size_t)(q * 8 + s) * 32 + f) * 8 + wave) * 64 + l4 * 16 + l15];
      acc[0] += w[s][0] * bf2f((unsigned short)(v.x & 0xFFFFu));
      acc[1] += w[s][1] * bf2f((unsigned short)(v.x >> 16));
      acc[2] += w[s][2] * bf2f((unsigned short)(v.y & 0xFFFFu));
      acc[3] += w[s][3] * bf2f((unsigned short)(v.y >> 16));
    }
    int col = f * 16 + l15;
#pragma unroll
    for (int r = 0; r < 4; r++)
      out[(size_t)(row0 + r) * 512 + col] = acc[r] * inv[r];
  }
}

extern "C" void kernel_launch(void* const* d_in, const int* in_sizes, int n_in,
                              void* d_out, int out_size, void* d_ws, size_t ws_size,
                              hipStream_t stream) {
  const void* Q   = d_in[0];
  const void* K   = d_in[1];
  const void* V   = d_in[2];
  const void* WQw = d_in[3];
  const void* WQb = d_in[4];
  const void* WKw = d_in[5];
  const void* WKb = d_in[6];
  const void* mask = d_in[7];
  float* out = (float*)d_out;
  char* ws = (char*)d_ws;
  (void)in_sizes; (void)n_in; (void)out_size; (void)ws_size;

  constexpr size_t SZ_MAT = (size_t)8192 * 512 * 2;  // 8 MB bf16
  size_t off = 4096;
  unsigned short* Qb  = (unsigned short*)(ws + off); off += SZ_MAT;
  unsigned short* Kb  = (unsigned short*)(ws + off); off += SZ_MAT;
  unsigned short* Wqb = (unsigned short*)(ws + off); off += (size_t)512 * 512 * 2;
  unsigned short* Wkb = (unsigned short*)(ws + off); off += (size_t)512 * 512 * 2;
  unsigned short* bqb = (unsigned short*)(ws + off); off += 1024;
  unsigned short* bkb = (unsigned short*)(ws + off); off += 1024;
  unsigned short* Vt  = (unsigned short*)(ws + off); off += SZ_MAT;
  unsigned short* Qp  = (unsigned short*)(ws + off); off += SZ_MAT;
  unsigned short* Kp  = (unsigned short*)(ws + off); off += SZ_MAT;
  unsigned long long* mbits = (unsigned long long*)(ws + off); off += (size_t)8192 * 128 * 8;
  unsigned short* Opart = (unsigned short*)(ws + off); off += (size_t)512 * 512 * 32 * 8;  // 64 MB
  float* mpart = (float*)(ws + off); off += (size_t)8 * 8192 * 4;
  float* lpart = (float*)(ws + off); off += (size_t)8 * 8192 * 4;
  int* fflag = (int*)ws;
  int* esize = (int*)(ws + 64);

  k_detect<<<2, 64, 0, stream>>>((const unsigned int*)Q, (const unsigned int*)mask, fflag, esize);
  k_prep<<<4354, 256, 0, stream>>>(Q, Qb, K, Kb, WQw, Wqb, WKw, Wkb, WQb, bqb, WKb, bkb, fflag);
  k_transpose_v<<<dim3(128, 8), 256, 0, stream>>>(V, fflag, Vt);
  k_pack<<<1024, 256, 0, stream>>>(mask, esize, mbits);
  k_proj<<<dim3(64, 4, 2), 256, 0, stream>>>(Qb, Wqb, bqb, Qp, Kb, Wkb, bkb, Kp);
  k_attn<<<512, 512, 0, stream>>>(Qp, Kp, Vt, mbits, Opart, mpart, lpart);
  k_combine<<<dim3(64, 2), 512, 0, stream>>>(Opart, mpart, lpart, out);
}

// Round 8
// 813.098 us; speedup vs baseline: 1.0700x; 1.0057x over previous
//
#include <hip/hip_runtime.h>

typedef __attribute__((ext_vector_type(8))) short short8;
typedef __attribute__((ext_vector_type(4))) float f32x4;

#define DEVFN __device__ __forceinline__

constexpr float NEGF = -4294967296.0f;              // -(1<<32)
// 1/sqrt(512) * log2(e): folded into Qp by k_proj; softmax runs in base-2.
constexpr float SCALE_LOG2E = 0.06375872465057373f;

DEVFN unsigned short f2bf(float f) {
  unsigned int u = __float_as_uint(f);
  u += 0x7FFFu + ((u >> 16) & 1u);   // RNE (inputs finite)
  return (unsigned short)(u >> 16);
}
DEVFN float bf2f(unsigned short h) { return __uint_as_float((unsigned)h << 16); }

DEVFN float exp2v(float x) {  // raw v_exp_f32: D = 2^S0 (no log2e mul)
  float r;
  asm("v_exp_f32 %0, %1" : "=v"(r) : "v"(x));
  return r;
}

DEVFN void gl_lds16(const void* g, void* l) {
  __builtin_amdgcn_global_load_lds(
      (const __attribute__((address_space(1))) unsigned int*)g,
      (__attribute__((address_space(3))) unsigned int*)l, 16, 0, 0);
}

// 16-lane butterfly reductions on the VALU (DPP) instead of ds_swizzle (LDS pipe).
DEVFN float dpp_fmax16(float x) {
  int v;
  v = __builtin_amdgcn_update_dpp(0, __float_as_int(x), 0xB1, 0xF, 0xF, true);
  x = fmaxf(x, __int_as_float(v));
  v = __builtin_amdgcn_update_dpp(0, __float_as_int(x), 0x4E, 0xF, 0xF, true);
  x = fmaxf(x, __int_as_float(v));
  v = __builtin_amdgcn_update_dpp(0, __float_as_int(x), 0x141, 0xF, 0xF, true);
  x = fmaxf(x, __int_as_float(v));
  v = __builtin_amdgcn_update_dpp(0, __float_as_int(x), 0x140, 0xF, 0xF, true);
  x = fmaxf(x, __int_as_float(v));
  return x;
}
DEVFN float dpp_fadd16(float x) {
  int v;
  v = __builtin_amdgcn_update_dpp(0, __float_as_int(x), 0xB1, 0xF, 0xF, true);
  x += __int_as_float(v);
  v = __builtin_amdgcn_update_dpp(0, __float_as_int(x), 0x4E, 0xF, 0xF, true);
  x += __int_as_float(v);
  v = __builtin_amdgcn_update_dpp(0, __float_as_int(x), 0x141, 0xF, 0xF, true);
  x += __int_as_float(v);
  v = __builtin_amdgcn_update_dpp(0, __float_as_int(x), 0x140, 0xF, 0xF, true);
  x += __int_as_float(v);
  return x;
}

// ---------- merged detectors: block 0 = Q dtype, block 1 = mask esize ----------
__global__ void k_detect(const unsigned int* __restrict__ q, const unsigned int* __restrict__ m,
                         int* __restrict__ fflag, int* __restrict__ esize) {
  int lane = threadIdx.x;
  if (blockIdx.x == 0) {
    unsigned bad = 0;
    for (int i = 0; i < 64; i++) {
      unsigned v = q[i * 64 + lane];
      unsigned h = v & 0xFFFFu;
      unsigned e = (h >> 7) & 0xFFu;
      if (h != 0u && (e < 96u || e > 150u)) bad = 1;
    }
    unsigned long long anyb = __ballot(bad != 0);
    if (lane == 0) *fflag = (anyb == 0ULL) ? 1 : 0;
  } else {
    unsigned okd = 1, okh = 1, okb = 1;
    for (int i = 0; i < 64; i++) {
      unsigned v = m[i * 64 + lane];
      if (v > 1u && v != 0x3F800000u) okd = 0;   // int32/f32 0|1|1.0f
      unsigned h0 = v & 0xFFFFu, h1 = v >> 16;
      if ((h0 && h0 != 0x3F80u && h0 != 1u) || (h1 && h1 != 0x3F80u && h1 != 1u)) okh = 0;
      if (v & 0xFEFEFEFEu) okb = 0;
    }
    okd = (__ballot(okd == 0) == 0ULL);
    okh = (__ballot(okh == 0) == 0ULL);
    okb = (__ballot(okb == 0) == 0ULL);
    if (lane == 0) *esize = okd ? 4 : (okh ? 2 : 1);
  }
}

// ---------- fused convert-or-copy -> bf16 for Q,K,WQw,WKw,bq,bk ----------
__global__ void k_prep(const void* __restrict__ Q, unsigned short* __restrict__ Qb,
                       const void* __restrict__ K, unsigned short* __restrict__ Kb,
                       const void* __restrict__ Wq, unsigned short* __restrict__ Wqb,
                       const void* __restrict__ Wk, unsigned short* __restrict__ Wkb,
                       const void* __restrict__ bq, unsigned short* __restrict__ bqb,
                       const void* __restrict__ bk, unsigned short* __restrict__ bkb,
                       const int* __restrict__ bf16flag) {
  int blk = blockIdx.x;
  const void* src; unsigned short* dst; int base, n;
  if (blk < 2048)      { src = Q;  dst = Qb;  base = blk;        n = 8192 * 512; }
  else if (blk < 4096) { src = K;  dst = Kb;  base = blk - 2048; n = 8192 * 512; }
  else if (blk < 4224) { src = Wq; dst = Wqb; base = blk - 4096; n = 512 * 512; }
  else if (blk < 4352) { src = Wk; dst = Wkb; base = blk - 4224; n = 512 * 512; }
  else if (blk == 4352){ src = bq; dst = bqb; base = 0;          n = 512; }
  else                 { src = bk; dst = bkb; base = 0;          n = 512; }
  int i = (base * 256 + threadIdx.x) * 8;
  if (i >= n) return;
  if (*bf16flag) {
    *(uint4*)(dst + i) = *(const uint4*)((const unsigned short*)src + i);
  } else {
    const float* f = (const float*)src + i;
    float4 a = *(const float4*)f, b = *(const float4*)(f + 4);
    uint4 o;
    o.x = (unsigned)f2bf(a.x) | ((unsigned)f2bf(a.y) << 16);
    o.y = (unsigned)f2bf(a.z) | ((unsigned)f2bf(a.w) << 16);
    o.z = (unsigned)f2bf(b.x) | ((unsigned)f2bf(b.y) << 16);
    o.w = (unsigned)f2bf(b.z) | ((unsigned)f2bf(b.w) << 16);
    *(uint4*)(dst + i) = o;
  }
}

// ---------- V [8192x512] -> tiled V^T: Vt[t][d][c], tiles of 32 k-rows ----------
__global__ void k_transpose_v(const void* __restrict__ Vsrc, const int* __restrict__ bf16flag,
                              unsigned short* __restrict__ Vt) {
  __shared__ unsigned short T[64][72];
  int t = threadIdx.x;
  int rb = blockIdx.x, cb = blockIdx.y;
  int r = t >> 3, c8 = (t & 7) * 8;
  int isbf = *bf16flag;
#pragma unroll
  for (int j = 0; j < 2; j++) {
    int row = rb * 64 + j * 32 + r;
    unsigned short e[8];
    if (isbf) {
      alignas(16) unsigned short tmp[8];
      *(uint4*)tmp = *(const uint4*)((const unsigned short*)Vsrc + (size_t)row * 512 + cb * 64 + c8);
#pragma unroll
      for (int i = 0; i < 8; i++) e[i] = tmp[i];
    } else {
      const float* f = (const float*)Vsrc + (size_t)row * 512 + cb * 64 + c8;
      float4 a = *(const float4*)f, b = *(const float4*)(f + 4);
      e[0] = f2bf(a.x); e[1] = f2bf(a.y); e[2] = f2bf(a.z); e[3] = f2bf(a.w);
      e[4] = f2bf(b.x); e[5] = f2bf(b.y); e[6] = f2bf(b.z); e[7] = f2bf(b.w);
    }
#pragma unroll
    for (int i = 0; i < 8; i++) T[c8 + i][j * 32 + r] = e[i];
  }
  __syncthreads();
#pragma unroll
  for (int j = 0; j < 2; j++) {
    int d = cb * 64 + j * 32 + r;                   // V col = V^T row
    alignas(16) unsigned short o[8];
#pragma unroll
    for (int i = 0; i < 8; i++) o[i] = T[j * 32 + r][c8 + i];
    int tt = rb * 2 + (c8 >> 5);
    *(uint4*)(Vt + ((size_t)tt * 512 + d) * 32 + (c8 & 31)) = *(const uint4*)o;
  }
}

// ---------- mask -> bit-packed row-major [8192][128] uint64 ----------
DEVFN unsigned nib4(unsigned v) {
  unsigned t = v; t |= t >> 1; t |= t >> 2; t |= t >> 4; t &= 0x01010101u;
  return (t * 0x10204080u) >> 28;
}
DEVFN unsigned pair2(unsigned v) {
  unsigned t = v; t |= t >> 8; t |= t >> 4; t |= t >> 2; t |= t >> 1;
  return (t & 1u) | (((t >> 16) & 1u) << 1);
}
__global__ void k_pack(const void* __restrict__ mask, const int* __restrict__ esize,
                       unsigned long long* __restrict__ bits) {
  int wv = (blockIdx.x * blockDim.x + threadIdx.x) >> 6;  // 4096 waves
  int lane = threadIdx.x & 63;
  int sz = *esize;
  if (sz == 4) {
    const unsigned int* m = (const unsigned int*)mask;
    for (int g = wv; g < 262144; g += 4096) {
      size_t base = (size_t)g * 256 + lane;
      unsigned v0 = m[base], v1 = m[base + 64], v2 = m[base + 128], v3 = m[base + 192];
      unsigned long long b0 = __ballot(v0 != 0u);
      unsigned long long b1 = __ballot(v1 != 0u);
      unsigned long long b2 = __ballot(v2 != 0u);
      unsigned long long b3 = __ballot(v3 != 0u);
      if (lane == 0) {
        bits[g * 4 + 0] = b0; bits[g * 4 + 1] = b1;
        bits[g * 4 + 2] = b2; bits[g * 4 + 3] = b3;
      }
    }
  } else if (sz == 2) {
    const uint4* m = (const uint4*)mask;
    for (int g = wv; g < 131072; g += 4096) {
      uint4 v = m[(size_t)g * 64 + lane];
      unsigned c8 = pair2(v.x) | (pair2(v.y) << 2) | (pair2(v.z) << 4) | (pair2(v.w) << 6);
      unsigned long long x = (unsigned long long)c8 << ((lane & 7) * 8);
      x |= __shfl_xor(x, 1); x |= __shfl_xor(x, 2); x |= __shfl_xor(x, 4);
      if ((lane & 7) == 0) bits[g * 8 + (lane >> 3)] = x;
    }
  } else {
    const uint4* m = (const uint4*)mask;
    for (int g = wv; g < 65536; g += 4096) {
      uint4 v = m[(size_t)g * 64 + lane];
      unsigned c16 = nib4(v.x) | (nib4(v.y) << 4) | (nib4(v.z) << 8) | (nib4(v.w) << 12);
      unsigned long long x = (unsigned long long)c16 << ((lane & 3) * 16);
      x |= __shfl_xor(x, 1); x |= __shfl_xor(x, 2);
      if ((lane & 3) == 0) bits[g * 16 + (lane >> 2)] = x;
    }
  }
}

// ---------- fused proj GEMM (z=0: Q, z=1: K): out = (A @ W^T + bias)*sc, bf16 ----------
// z=0 (Q side) folds SCALE_LOG2E so k_attn's softmax runs in base-2 with no muls.
__global__ __launch_bounds__(256, 2) void k_proj(
    const unsigned short* __restrict__ Aq, const unsigned short* __restrict__ Wq,
    const unsigned short* __restrict__ bq, unsigned short* __restrict__ outq,
    const unsigned short* __restrict__ Ak, const unsigned short* __restrict__ Wk,
    const unsigned short* __restrict__ bk, unsigned short* __restrict__ outk) {
  const unsigned short* A = blockIdx.z ? Ak : Aq;
  const unsigned short* W = blockIdx.z ? Wk : Wq;
  const unsigned short* bias = blockIdx.z ? bk : bq;
  unsigned short* out = blockIdx.z ? outk : outq;
  float sc = blockIdx.z ? 1.0f : SCALE_LOG2E;

  __shared__ alignas(16) unsigned short As[128 * 64];
  __shared__ alignas(16) unsigned short Bs[128 * 64];
  int tid = threadIdx.x, lane = tid & 63, wave = tid >> 6;
  int wi = wave >> 1, wj = wave & 1;
  int l15 = lane & 15, l4 = lane >> 4;
  int rowbase = blockIdx.x * 128, colbase = blockIdx.y * 128;
  f32x4 acc[4][4];
#pragma unroll
  for (int i = 0; i < 4; i++)
#pragma unroll
    for (int j = 0; j < 4; j++) acc[i][j] = f32x4{0.f, 0.f, 0.f, 0.f};

  int swr = l15 & 7;
  for (int kb = 0; kb < 512; kb += 64) {
    __syncthreads();
#pragma unroll
    for (int t = 0; t < 4; t++) {
      int inst = wave * 4 + t;
      int r = inst * 8 + (lane >> 3);
      int c = ((lane & 7) ^ (r & 7)) * 8;
      gl_lds16(A + (size_t)(rowbase + r) * 512 + kb + c, &As[inst * 512]);
      gl_lds16(W + (size_t)(colbase + r) * 512 + kb + c, &Bs[inst * 512]);
    }
    __syncthreads();
#pragma unroll
    for (int t2 = 0; t2 < 2; t2++) {
      short8 a[4], b[4];
#pragma unroll
      for (int i = 0; i < 4; i++) {
        int row = wi * 64 + i * 16 + l15;
        a[i] = *(const short8*)&As[row * 64 + (((t2 * 4 + l4) ^ swr) * 8)];
      }
#pragma unroll
      for (int j = 0; j < 4; j++) {
        int row = wj * 64 + j * 16 + l15;
        b[j] = *(const short8*)&Bs[row * 64 + (((t2 * 4 + l4) ^ swr) * 8)];
      }
#pragma unroll
      for (int i = 0; i < 4; i++)
#pragma unroll
        for (int j = 0; j < 4; j++)
          acc[i][j] = __builtin_amdgcn_mfma_f32_16x16x32_bf16(a[i], b[j], acc[i][j], 0, 0, 0);
    }
  }
#pragma unroll
  for (int j = 0; j < 4; j++) {
    int col = colbase + wj * 64 + j * 16 + l15;
    float bj = bf2f(bias[col]);
#pragma unroll
    for (int i = 0; i < 4; i++) {
      int row0 = rowbase + wi * 64 + i * 16 + l4 * 4;
#pragma unroll
      for (int r = 0; r < 4; r++)
        out[(size_t)(row0 + r) * 512 + col] = f2bf((acc[i][j][r] + bj) * sc);
    }
  }
}

// ---------- flash attention: BM=128 (8 waves), BN=32, split-K=8 ----------
// v9 = v8 with the stagger PAIRING FIXED. v8 split phases by (wave&1), but
// waves map to SIMDs round-robin (wave i -> SIMD i&3): SIMD0 got waves {0,4}
// (both "even"), SIMD1 {1,5} (both "odd") -- every SIMD ran two SAME-phase
// waves and the intended MFMA||VALU overlap never existed. v9 splits by
// (wave>>2): SIMD s hosts wave s (SM-first) and wave s+4 (PV-first), so each
// SIMD always has one wave in an MFMA cluster and one in softmax VALU.
// Everything else identical to v8 (counted-vmcnt single-barrier pipeline,
// 1 lockstep block/CU, base-2 softmax, deferred li, select-only mask).
__global__ __launch_bounds__(512, 2) void k_attn(
    const unsigned short* __restrict__ Qp, const unsigned short* __restrict__ Kp,
    const unsigned short* __restrict__ Vt, const unsigned long long* __restrict__ mbits,
    unsigned short* __restrict__ Opart, float* __restrict__ mpart, float* __restrict__ lpart) {
  __shared__ alignas(16) unsigned short KB[2][16384];   // 2 x 32 k-rows x 512 (col-swizzled)
  __shared__ alignas(16) unsigned short VB[16384];      // 512 d-rows x 32 (chunk-swizzled)
  __shared__ alignas(16) unsigned short P2[2][4][128][8];  // 2 x [koct][q-row][8]
  __shared__ alignas(16) float alds[2][128];            // per-row rescale factor
  __shared__ alignas(16) int nfl[2][8];                 // per-wave rescale flags
  int tid = threadIdx.x, lane = tid & 63, wave = tid >> 6;
  int l15 = lane & 15, l4 = lane >> 4;
  int b = blockIdx.x;
  int split = b & 7;
  int qb = (b >> 3) * 128;

  short8 qf[16];  // persistent Q fragments: wave's 16 rows x 512
  {
    int row = qb + wave * 16 + l15;
#pragma unroll
    for (int t = 0; t < 16; t++)
      qf[t] = *(const short8*)(Qp + (size_t)row * 512 + t * 32 + l4 * 8);
  }
  f32x4 o[8][4];  // all 128 rows x wave's 64 d-cols
#pragma unroll
  for (int i = 0; i < 8; i++)
#pragma unroll
    for (int j = 0; j < 4; j++) o[i][j] = f32x4{0.f, 0.f, 0.f, 0.f};
  float mi[4] = {NEGF, NEGF, NEGF, NEGF};
  float li_l[4] = {0.f, 0.f, 0.f, 0.f};   // per-lane partial row sums

  int swK = l15 | ((l15 & 3) << 4);   // K read swizzle (matches deposit swz(row))
  const unsigned int* mb32 = (const unsigned int*)mbits;

#define STAGE_K(TV, BUF)                                                         \
  {                                                                              \
    _Pragma("unroll") for (int t = 0; t < 4; t++) {                              \
      int r = wave * 4 + t;                                                      \
      int swz = (r & 15) | ((r & 3) << 4);                                       \
      gl_lds16(Kp + (size_t)((TV) * 32 + r) * 512 + ((lane ^ swz) * 8),          \
               &KB[BUF][r * 512]);                                               \
    }                                                                            \
  }
#define STAGE_V(TV)                                                              \
  {                                                                              \
    _Pragma("unroll") for (int t = 0; t < 4; t++) {                              \
      int inst = wave * 4 + t;                                                   \
      int d = inst * 16 + (lane >> 2);                                           \
      int cg = (lane & 3) ^ ((d >> 2) & 3);                                      \
      gl_lds16(Vt + (size_t)(TV) * 16384 + d * 32 + cg * 8, &VB[inst * 512]);    \
    }                                                                            \
  }
#define LOAD_MASKS(IT)                                                           \
  _Pragma("unroll") for (int r = 0; r < 4; r++)                                  \
    mw[r] = mb32[((size_t)(qb + wave * 16 + l4 * 4 + r) * 128 + split * 16 +     \
                  ((IT) >> 1)) * 2 + ((IT) & 1)];
// SM_BLOCK: QK^T + mask + base-2 deferred-max softmax + P2 write (buffer CUR)
#define SM_BLOCK(CUR)                                                            \
  {                                                                              \
    f32x4 sacc[2];                                                               \
    _Pragma("unroll") for (int c = 0; c < 2; c++) sacc[c] = f32x4{0.f,0.f,0.f,0.f}; \
    __builtin_amdgcn_s_setprio(1);                                               \
    _Pragma("unroll") for (int t2 = 0; t2 < 16; t2++) {                          \
      short8 a = qf[t2];                                                         \
      _Pragma("unroll") for (int c = 0; c < 2; c++) {                            \
        int row = c * 16 + l15;                                                  \
        short8 bb = *(const short8*)&KB[CUR][row * 512 + (((t2 * 4 + l4) ^ swK) * 8)]; \
        sacc[c] = __builtin_amdgcn_mfma_f32_16x16x32_bf16(a, bb, sacc[c], 0, 0, 0); \
      }                                                                          \
    }                                                                            \
    __builtin_amdgcn_s_setprio(0);                                               \
    _Pragma("unroll") for (int c = 0; c < 2; c++)                                \
      _Pragma("unroll") for (int r = 0; r < 4; r++) {                            \
        bool msk = (mw[r] >> (c * 16 + l15)) & 1u;                               \
        sacc[c][r] = msk ? NEGF : sacc[c][r];                                    \
      }                                                                          \
    float al4[4];                                                                \
    bool need = false;                                                           \
    _Pragma("unroll") for (int r = 0; r < 4; r++) {                              \
      float t = dpp_fmax16(fmaxf(sacc[0][r], sacc[1][r]));                       \
      al4[r] = t;                                                                \
      need |= (t > mi[r] + 11.5f);                                               \
    }                                                                            \
    unsigned long long blt = __ballot(need);                                     \
    if (lane == 0) nfl[CUR][wave] = (blt != 0ULL) ? 1 : 0;                       \
    if (blt) {                                                                   \
      _Pragma("unroll") for (int r = 0; r < 4; r++) {                            \
        float mn = fmaxf(mi[r], al4[r]);                                         \
        float a = exp2v(mi[r] - mn);                                             \
        li_l[r] *= a;                                                            \
        mi[r] = mn;                                                              \
        al4[r] = a;                                                              \
      }                                                                          \
    } else {                                                                     \
      _Pragma("unroll") for (int r = 0; r < 4; r++) al4[r] = 1.0f;               \
    }                                                                            \
    if (l15 == 0) *(f32x4*)&alds[CUR][wave * 16 + l4 * 4] =                      \
        f32x4{al4[0], al4[1], al4[2], al4[3]};                                   \
    _Pragma("unroll") for (int r = 0; r < 4; r++) {                              \
      sacc[0][r] = exp2v(sacc[0][r] - mi[r]);                                    \
      sacc[1][r] = exp2v(sacc[1][r] - mi[r]);                                    \
      li_l[r] += sacc[0][r] + sacc[1][r];                                        \
    }                                                                            \
    _Pragma("unroll") for (int r = 0; r < 4; r++) {                              \
      int prow = wave * 16 + l4 * 4 + r;                                         \
      _Pragma("unroll") for (int c = 0; c < 2; c++)                              \
        P2[CUR][c * 2 + (l15 >> 3)][prow][l15 & 7] = f2bf(sacc[c][r]);           \
    }                                                                            \
  }
// PV_BLOCK: deferred o-rescale + P(prv)@V MFMAs (VB is wave-private)
#define PV_BLOCK(PRV)                                                            \
  {                                                                              \
    __builtin_amdgcn_s_waitcnt(0x0F78); /* vmcnt(8): V(it-1) landed */           \
    __builtin_amdgcn_sched_barrier(0);                                           \
    {                                                                            \
      const int4* n4 = (const int4*)&nfl[PRV][0];                                \
      int4 na = n4[0], nb4 = n4[1];                                              \
      if (na.x | na.y | na.z | na.w | nb4.x | nb4.y | nb4.z | nb4.w) {           \
        _Pragma("unroll") for (int rf = 0; rf < 8; rf++) {                       \
          f32x4 av = *(const f32x4*)&alds[PRV][rf * 16 + l4 * 4];                \
          _Pragma("unroll") for (int df = 0; df < 4; df++)                       \
            _Pragma("unroll") for (int j = 0; j < 4; j++) o[rf][df][j] *= av[j]; \
        }                                                                        \
      }                                                                          \
    }                                                                            \
    short8 vf[4];                                                                \
    _Pragma("unroll") for (int df = 0; df < 4; df++) {                           \
      int d = wave * 64 + df * 16 + l15;                                         \
      vf[df] = *(const short8*)&VB[d * 32 + ((l4 ^ ((l15 >> 2) & 3)) * 8)];      \
    }                                                                            \
    __builtin_amdgcn_s_setprio(1);                                               \
    _Pragma("unroll") for (int rf = 0; rf < 8; rf++) {                           \
      short8 pa = *(const short8*)&P2[PRV][l4][rf * 16 + l15][0];                \
      _Pragma("unroll") for (int df = 0; df < 4; df++)                           \
        o[rf][df] = __builtin_amdgcn_mfma_f32_16x16x32_bf16(pa, vf[df],          \
                                                            o[rf][df], 0, 0, 0);\
    }                                                                            \
    __builtin_amdgcn_s_setprio(0);                                               \
  }

  // prologue: stage K(0) -> KB[0], drain, sync
  STAGE_K(split * 32, 0);
  __builtin_amdgcn_s_waitcnt(0x0F70);  // vmcnt(0)
  __builtin_amdgcn_s_barrier();

  // ---- iteration 0: SM only (no PV yet) ----
  {
    const int tv = split * 32;
    unsigned mw[4];
    LOAD_MASKS(0);
    asm volatile("" ::: "memory");  // pin masks before the gl_lds issues
    STAGE_K(tv + 1, 1);
    SM_BLOCK(0);
    STAGE_V(tv);
    __builtin_amdgcn_s_waitcnt(0x0074);  // vmcnt(4) lgkmcnt(0): K(1) landed, V(0) flies
    __builtin_amdgcn_s_barrier();
  }

  // ---- main loop: SIMD-paired stagger {SM(it), PV(it-1)} ----
  // waves 0-3 SM-first, waves 4-7 PV-first: SIMD s = {wave s, wave s+4},
  // one MFMA-cluster wave + one VALU wave per SIMD at all times.
  const bool smFirst = (wave >> 2) == 0;
  for (int it = 1; it < 32; ++it) {
    const int cur = it & 1, prv = cur ^ 1;
    const int tv = split * 32 + it;

    unsigned mw[4];
    LOAD_MASKS(it);
    asm volatile("" ::: "memory");
    STAGE_K((it < 31) ? tv + 1 : tv, prv);

    if (smFirst) {
      SM_BLOCK(cur);   // softmax VALU here overlaps partner wave's PV MFMAs
      PV_BLOCK(prv);
    } else {
      PV_BLOCK(prv);   // PV MFMAs here overlap partner wave's softmax VALU
      SM_BLOCK(cur);
    }

    STAGE_V(tv);
    __builtin_amdgcn_s_waitcnt(0x0074);  // vmcnt(4) lgkmcnt(0): K(it+1) landed, V(it) flies
    __builtin_amdgcn_s_barrier();
  }

  // ---- epilogue PV(31): buffers [1] ----
  __builtin_amdgcn_s_waitcnt(0x0F70);  // vmcnt(0): V(31) landed
  __builtin_amdgcn_sched_barrier(0);
  PV_BLOCK(1);

  // ---- epilogue: reduce li, store m/l + fragment-layout bf16 partials ----
  float li[4];
#pragma unroll
  for (int r = 0; r < 4; r++) li[r] = dpp_fadd16(li_l[r]);
#pragma unroll
  for (int r = 0; r < 4; r++) {
    int row = qb + wave * 16 + l4 * 4 + r;
    if (l15 == 0) {
      mpart[(size_t)split * 8192 + row] = mi[r];
      lpart[(size_t)split * 8192 + row] = li[r];
    }
  }
  uint2* op2 = (uint2*)Opart;
#pragma unroll
  for (int rf = 0; rf < 8; rf++)
#pragma unroll
    for (int df = 0; df < 4; df++) {
      int f = wave * 4 + df;   // global 16-col d-frag index 0..31
      uint2 v;
      v.x = (unsigned)f2bf(o[rf][df][0]) | ((unsigned)f2bf(o[rf][df][1]) << 16);
      v.y = (unsigned)f2bf(o[rf][df][2]) | ((unsigned)f2bf(o[rf][df][3]) << 16);
      op2[(((size_t)b * 32 + f) * 8 + rf) * 64 + l4 * 16 + l15] = v;
    }
#undef STAGE_K
#undef STAGE_V
#undef LOAD_MASKS
#undef SM_BLOCK
#undef PV_BLOCK
}

// ---------- combine 8 split-K partials (base-2 weights) -> f32 out ----------
__global__ void k_combine(const unsigned short* __restrict__ Opart,
                          const float* __restrict__ mpart, const float* __restrict__ lpart,
                          float* __restrict__ out) {
  int q = blockIdx.x;                 // 0..63 (128-row tile)
  int half = blockIdx.y;              // 0..1
  int tid = threadIdx.x;              // 512 threads
  int wave = tid >> 6, lane = tid & 63, l4 = (lane >> 4) & 3, l15 = lane & 15;
  int row0 = q * 128 + wave * 16 + l4 * 4;

  float w[8][4], inv[4];
#pragma unroll
  for (int r = 0; r < 4; r++) {
    float M = NEGF;
    float mv[8];
#pragma unroll
    for (int s = 0; s < 8; s++) { mv[s] = mpart[s * 8192 + row0 + r]; M = fmaxf(M, mv[s]); }
    float L = 0.f;
#pragma unroll
    for (int s = 0; s < 8; s++) {
      float ws = exp2v(mv[s] - M);    // log2-domain partial maxima
      w[s][r] = ws;
      L += ws * lpart[s * 8192 + row0 + r];
    }
    inv[r] = 1.0f / L;
  }
  const uint2* op2 = (const uint2*)Opart;
#pragma unroll
  for (int fo = 0; fo < 16; fo++) {
    int f = half * 16 + fo;
    float acc[4] = {0.f, 0.f, 0.f, 0.f};
#pragma unroll
    for (int s = 0; s < 8; s++) {
      uint2 v = op2[(((size_t)(q * 8 + s) * 32 + f) * 8 + wave) * 64 + l4 * 16 + l15];
      acc[0] += w[s][0] * bf2f((unsigned short)(v.x & 0xFFFFu));
      acc[1] += w[s][1] * bf2f((unsigned short)(v.x >> 16));
      acc[2] += w[s][2] * bf2f((unsigned short)(v.y & 0xFFFFu));
      acc[3] += w[s][3] * bf2f((unsigned short)(v.y >> 16));
    }
    int col = f * 16 + l15;
#pragma unroll
    for (int r = 0; r < 4; r++)
      out[(size_t)(row0 + r) * 512 + col] = acc[r] * inv[r];
  }
}

extern "C" void kernel_launch(void* const* d_in, const int* in_sizes, int n_in,
                              void* d_out, int out_size, void* d_ws, size_t ws_size,
                              hipStream_t stream) {
  const void* Q   = d_in[0];
  const void* K   = d_in[1];
  const void* V   = d_in[2];
  const void* WQw = d_in[3];
  const void* WQb = d_in[4];
  const void* WKw = d_in[5];
  const void* WKb = d_in[6];
  const void* mask = d_in[7];
  float* out = (float*)d_out;
  char* ws = (char*)d_ws;
  (void)in_sizes; (void)n_in; (void)out_size; (void)ws_size;

  constexpr size_t SZ_MAT = (size_t)8192 * 512 * 2;  // 8 MB bf16
  size_t off = 4096;
  unsigned short* Qb  = (unsigned short*)(ws + off); off += SZ_MAT;
  unsigned short* Kb  = (unsigned short*)(ws + off); off += SZ_MAT;
  unsigned short* Wqb = (unsigned short*)(ws + off); off += (size_t)512 * 512 * 2;
  unsigned short* Wkb = (unsigned short*)(ws + off); off += (size_t)512 * 512 * 2;
  unsigned short* bqb = (unsigned short*)(ws + off); off += 1024;
  unsigned short* bkb = (unsigned short*)(ws + off); off += 1024;
  unsigned short* Vt  = (unsigned short*)(ws + off); off += SZ_MAT;
  unsigned short* Qp  = (unsigned short*)(ws + off); off += SZ_MAT;
  unsigned short* Kp  = (unsigned short*)(ws + off); off += SZ_MAT;
  unsigned long long* mbits = (unsigned long long*)(ws + off); off += (size_t)8192 * 128 * 8;
  unsigned short* Opart = (unsigned short*)(ws + off); off += (size_t)512 * 512 * 32 * 8;  // 64 MB
  float* mpart = (float*)(ws + off); off += (size_t)8 * 8192 * 4;
  float* lpart = (float*)(ws + off); off += (size_t)8 * 8192 * 4;
  int* fflag = (int*)ws;
  int* esize = (int*)(ws + 64);

  k_detect<<<2, 64, 0, stream>>>((const unsigned int*)Q, (const unsigned int*)mask, fflag, esize);
  k_prep<<<4354, 256, 0, stream>>>(Q, Qb, K, Kb, WQw, Wqb, WKw, Wkb, WQb, bqb, WKb, bkb, fflag);
  k_transpose_v<<<dim3(128, 8), 256, 0, stream>>>(V, fflag, Vt);
  k_pack<<<1024, 256, 0, stream>>>(mask, esize, mbits);
  k_proj<<<dim3(64, 4, 2), 256, 0, stream>>>(Qb, Wqb, bqb, Qp, Kb, Wkb, bkb, Kp);
  k_attn<<<512, 512, 0, stream>>>(Qp, Kp, Vt, mbits, Opart, mpart, lpart);
  k_combine<<<dim3(64, 2), 512, 0, stream>>>(Opart, mpart, lpart, out);
}

// Round 9
// 778.449 us; speedup vs baseline: 1.1176x; 1.0445x over previous
//
#include <hip/hip_runtime.h>

typedef __attribute__((ext_vector_type(8))) short short8;
typedef __attribute__((ext_vector_type(4))) float f32x4;

#define DEVFN __device__ __forceinline__

constexpr float NEGF = -4294967296.0f;              // -(1<<32)
// 1/sqrt(512) * log2(e): folded into Qp by k_proj; k_attn softmax runs base-2.
constexpr float SCALE_LOG2E = 0.06375872465057373f;

DEVFN unsigned short f2bf(float f) {
  unsigned int u = __float_as_uint(f);
  u += 0x7FFFu + ((u >> 16) & 1u);   // RNE (inputs finite)
  return (unsigned short)(u >> 16);
}
DEVFN float bf2f(unsigned short h) { return __uint_as_float((unsigned)h << 16); }

DEVFN float exp2v(float x) {  // raw v_exp_f32: D = 2^S0 (no log2e mul)
  float r;
  asm("v_exp_f32 %0, %1" : "=v"(r) : "v"(x));
  return r;
}

DEVFN void gl_lds16(const void* g, void* l) {
  __builtin_amdgcn_global_load_lds(
      (const __attribute__((address_space(1))) unsigned int*)g,
      (__attribute__((address_space(3))) unsigned int*)l, 16, 0, 0);
}

// 16-lane butterfly reductions on the VALU (DPP) instead of ds_swizzle (LDS pipe).
DEVFN float dpp_fmax16(float x) {
  int v;
  v = __builtin_amdgcn_update_dpp(0, __float_as_int(x), 0xB1, 0xF, 0xF, true);
  x = fmaxf(x, __int_as_float(v));
  v = __builtin_amdgcn_update_dpp(0, __float_as_int(x), 0x4E, 0xF, 0xF, true);
  x = fmaxf(x, __int_as_float(v));
  v = __builtin_amdgcn_update_dpp(0, __float_as_int(x), 0x141, 0xF, 0xF, true);
  x = fmaxf(x, __int_as_float(v));
  v = __builtin_amdgcn_update_dpp(0, __float_as_int(x), 0x140, 0xF, 0xF, true);
  x = fmaxf(x, __int_as_float(v));
  return x;
}
DEVFN float dpp_fadd16(float x) {
  int v;
  v = __builtin_amdgcn_update_dpp(0, __float_as_int(x), 0xB1, 0xF, 0xF, true);
  x += __int_as_float(v);
  v = __builtin_amdgcn_update_dpp(0, __float_as_int(x), 0x4E, 0xF, 0xF, true);
  x += __int_as_float(v);
  v = __builtin_amdgcn_update_dpp(0, __float_as_int(x), 0x141, 0xF, 0xF, true);
  x += __int_as_float(v);
  v = __builtin_amdgcn_update_dpp(0, __float_as_int(x), 0x140, 0xF, 0xF, true);
  x += __int_as_float(v);
  return x;
}

// ---------- merged detectors: block 0 = Q dtype, block 1 = mask esize ----------
__global__ void k_detect(const unsigned int* __restrict__ q, const unsigned int* __restrict__ m,
                         int* __restrict__ fflag, int* __restrict__ esize) {
  int lane = threadIdx.x;
  if (blockIdx.x == 0) {
    unsigned bad = 0;
    for (int i = 0; i < 64; i++) {
      unsigned v = q[i * 64 + lane];
      unsigned h = v & 0xFFFFu;
      unsigned e = (h >> 7) & 0xFFu;
      if (h != 0u && (e < 96u || e > 150u)) bad = 1;
    }
    unsigned long long anyb = __ballot(bad != 0);
    if (lane == 0) *fflag = (anyb == 0ULL) ? 1 : 0;
  } else {
    unsigned okd = 1, okh = 1, okb = 1;
    for (int i = 0; i < 64; i++) {
      unsigned v = m[i * 64 + lane];
      if (v > 1u && v != 0x3F800000u) okd = 0;   // int32/f32 0|1|1.0f
      unsigned h0 = v & 0xFFFFu, h1 = v >> 16;
      if ((h0 && h0 != 0x3F80u && h0 != 1u) || (h1 && h1 != 0x3F80u && h1 != 1u)) okh = 0;
      if (v & 0xFEFEFEFEu) okb = 0;
    }
    okd = (__ballot(okd == 0) == 0ULL);
    okh = (__ballot(okh == 0) == 0ULL);
    okb = (__ballot(okb == 0) == 0ULL);
    if (lane == 0) *esize = okd ? 4 : (okh ? 2 : 1);
  }
}

// ---------- fused convert-or-copy -> bf16 for Q,K,WQw,WKw,bq,bk ----------
__global__ void k_prep(const void* __restrict__ Q, unsigned short* __restrict__ Qb,
                       const void* __restrict__ K, unsigned short* __restrict__ Kb,
                       const void* __restrict__ Wq, unsigned short* __restrict__ Wqb,
                       const void* __restrict__ Wk, unsigned short* __restrict__ Wkb,
                       const void* __restrict__ bq, unsigned short* __restrict__ bqb,
                       const void* __restrict__ bk, unsigned short* __restrict__ bkb,
                       const int* __restrict__ bf16flag) {
  int blk = blockIdx.x;
  const void* src; unsigned short* dst; int base, n;
  if (blk < 2048)      { src = Q;  dst = Qb;  base = blk;        n = 8192 * 512; }
  else if (blk < 4096) { src = K;  dst = Kb;  base = blk - 2048; n = 8192 * 512; }
  else if (blk < 4224) { src = Wq; dst = Wqb; base = blk - 4096; n = 512 * 512; }
  else if (blk < 4352) { src = Wk; dst = Wkb; base = blk - 4224; n = 512 * 512; }
  else if (blk == 4352){ src = bq; dst = bqb; base = 0;          n = 512; }
  else                 { src = bk; dst = bkb; base = 0;          n = 512; }
  int i = (base * 256 + threadIdx.x) * 8;
  if (i >= n) return;
  if (*bf16flag) {
    *(uint4*)(dst + i) = *(const uint4*)((const unsigned short*)src + i);
  } else {
    const float* f = (const float*)src + i;
    float4 a = *(const float4*)f, b = *(const float4*)(f + 4);
    uint4 o;
    o.x = (unsigned)f2bf(a.x) | ((unsigned)f2bf(a.y) << 16);
    o.y = (unsigned)f2bf(a.z) | ((unsigned)f2bf(a.w) << 16);
    o.z = (unsigned)f2bf(b.x) | ((unsigned)f2bf(b.y) << 16);
    o.w = (unsigned)f2bf(b.z) | ((unsigned)f2bf(b.w) << 16);
    *(uint4*)(dst + i) = o;
  }
}

// ---------- V [8192x512] -> tiled V^T: Vt[t][d][c], tiles of 32 k-rows ----------
__global__ void k_transpose_v(const void* __restrict__ Vsrc, const int* __restrict__ bf16flag,
                              unsigned short* __restrict__ Vt) {
  __shared__ unsigned short T[64][72];
  int t = threadIdx.x;
  int rb = blockIdx.x, cb = blockIdx.y;
  int r = t >> 3, c8 = (t & 7) * 8;
  int isbf = *bf16flag;
#pragma unroll
  for (int j = 0; j < 2; j++) {
    int row = rb * 64 + j * 32 + r;
    unsigned short e[8];
    if (isbf) {
      alignas(16) unsigned short tmp[8];
      *(uint4*)tmp = *(const uint4*)((const unsigned short*)Vsrc + (size_t)row * 512 + cb * 64 + c8);
#pragma unroll
      for (int i = 0; i < 8; i++) e[i] = tmp[i];
    } else {
      const float* f = (const float*)Vsrc + (size_t)row * 512 + cb * 64 + c8;
      float4 a = *(const float4*)f, b = *(const float4*)(f + 4);
      e[0] = f2bf(a.x); e[1] = f2bf(a.y); e[2] = f2bf(a.z); e[3] = f2bf(a.w);
      e[4] = f2bf(b.x); e[5] = f2bf(b.y); e[6] = f2bf(b.z); e[7] = f2bf(b.w);
    }
#pragma unroll
    for (int i = 0; i < 8; i++) T[c8 + i][j * 32 + r] = e[i];
  }
  __syncthreads();
#pragma unroll
  for (int j = 0; j < 2; j++) {
    int d = cb * 64 + j * 32 + r;                   // V col = V^T row
    alignas(16) unsigned short o[8];
#pragma unroll
    for (int i = 0; i < 8; i++) o[i] = T[j * 32 + r][c8 + i];
    int tt = rb * 2 + (c8 >> 5);
    *(uint4*)(Vt + ((size_t)tt * 512 + d) * 32 + (c8 & 31)) = *(const uint4*)o;
  }
}

// ---------- mask -> bit-packed row-major [8192][128] uint64 ----------
DEVFN unsigned nib4(unsigned v) {
  unsigned t = v; t |= t >> 1; t |= t >> 2; t |= t >> 4; t &= 0x01010101u;
  return (t * 0x10204080u) >> 28;
}
DEVFN unsigned pair2(unsigned v) {
  unsigned t = v; t |= t >> 8; t |= t >> 4; t |= t >> 2; t |= t >> 1;
  return (t & 1u) | (((t >> 16) & 1u) << 1);
}
__global__ void k_pack(const void* __restrict__ mask, const int* __restrict__ esize,
                       unsigned long long* __restrict__ bits) {
  int wv = (blockIdx.x * blockDim.x + threadIdx.x) >> 6;  // 4096 waves
  int lane = threadIdx.x & 63;
  int sz = *esize;
  if (sz == 4) {
    const unsigned int* m = (const unsigned int*)mask;
    for (int g = wv; g < 262144; g += 4096) {
      size_t base = (size_t)g * 256 + lane;
      unsigned v0 = m[base], v1 = m[base + 64], v2 = m[base + 128], v3 = m[base + 192];
      unsigned long long b0 = __ballot(v0 != 0u);
      unsigned long long b1 = __ballot(v1 != 0u);
      unsigned long long b2 = __ballot(v2 != 0u);
      unsigned long long b3 = __ballot(v3 != 0u);
      if (lane == 0) {
        bits[g * 4 + 0] = b0; bits[g * 4 + 1] = b1;
        bits[g * 4 + 2] = b2; bits[g * 4 + 3] = b3;
      }
    }
  } else if (sz == 2) {
    const uint4* m = (const uint4*)mask;
    for (int g = wv; g < 131072; g += 4096) {
      uint4 v = m[(size_t)g * 64 + lane];
      unsigned c8 = pair2(v.x) | (pair2(v.y) << 2) | (pair2(v.z) << 4) | (pair2(v.w) << 6);
      unsigned long long x = (unsigned long long)c8 << ((lane & 7) * 8);
      x |= __shfl_xor(x, 1); x |= __shfl_xor(x, 2); x |= __shfl_xor(x, 4);
      if ((lane & 7) == 0) bits[g * 8 + (lane >> 3)] = x;
    }
  } else {
    const uint4* m = (const uint4*)mask;
    for (int g = wv; g < 65536; g += 4096) {
      uint4 v = m[(size_t)g * 64 + lane];
      unsigned c16 = nib4(v.x) | (nib4(v.y) << 4) | (nib4(v.z) << 8) | (nib4(v.w) << 12);
      unsigned long long x = (unsigned long long)c16 << ((lane & 3) * 16);
      x |= __shfl_xor(x, 1); x |= __shfl_xor(x, 2);
      if ((lane & 3) == 0) bits[g * 16 + (lane >> 2)] = x;
    }
  }
}

// ---------- fused proj GEMM (z=0: Q, z=1: K): out = (A @ W^T + bias)*sc, bf16 ----------
// z=0 (Q side) folds SCALE_LOG2E so k_attn's softmax runs in base-2 with no muls.
__global__ __launch_bounds__(256, 2) void k_proj(
    const unsigned short* __restrict__ Aq, const unsigned short* __restrict__ Wq,
    const unsigned short* __restrict__ bq, unsigned short* __restrict__ outq,
    const unsigned short* __restrict__ Ak, const unsigned short* __restrict__ Wk,
    const unsigned short* __restrict__ bk, unsigned short* __restrict__ outk) {
  const unsigned short* A = blockIdx.z ? Ak : Aq;
  const unsigned short* W = blockIdx.z ? Wk : Wq;
  const unsigned short* bias = blockIdx.z ? bk : bq;
  unsigned short* out = blockIdx.z ? outk : outq;
  float sc = blockIdx.z ? 1.0f : SCALE_LOG2E;

  __shared__ alignas(16) unsigned short As[128 * 64];
  __shared__ alignas(16) unsigned short Bs[128 * 64];
  int tid = threadIdx.x, lane = tid & 63, wave = tid >> 6;
  int wi = wave >> 1, wj = wave & 1;
  int l15 = lane & 15, l4 = lane >> 4;
  int rowbase = blockIdx.x * 128, colbase = blockIdx.y * 128;
  f32x4 acc[4][4];
#pragma unroll
  for (int i = 0; i < 4; i++)
#pragma unroll
    for (int j = 0; j < 4; j++) acc[i][j] = f32x4{0.f, 0.f, 0.f, 0.f};

  int swr = l15 & 7;
  for (int kb = 0; kb < 512; kb += 64) {
    __syncthreads();
#pragma unroll
    for (int t = 0; t < 4; t++) {
      int inst = wave * 4 + t;
      int r = inst * 8 + (lane >> 3);
      int c = ((lane & 7) ^ (r & 7)) * 8;
      gl_lds16(A + (size_t)(rowbase + r) * 512 + kb + c, &As[inst * 512]);
      gl_lds16(W + (size_t)(colbase + r) * 512 + kb + c, &Bs[inst * 512]);
    }
    __syncthreads();
#pragma unroll
    for (int t2 = 0; t2 < 2; t2++) {
      short8 a[4], b[4];
#pragma unroll
      for (int i = 0; i < 4; i++) {
        int row = wi * 64 + i * 16 + l15;
        a[i] = *(const short8*)&As[row * 64 + (((t2 * 4 + l4) ^ swr) * 8)];
      }
#pragma unroll
      for (int j = 0; j < 4; j++) {
        int row = wj * 64 + j * 16 + l15;
        b[j] = *(const short8*)&Bs[row * 64 + (((t2 * 4 + l4) ^ swr) * 8)];
      }
#pragma unroll
      for (int i = 0; i < 4; i++)
#pragma unroll
        for (int j = 0; j < 4; j++)
          acc[i][j] = __builtin_amdgcn_mfma_f32_16x16x32_bf16(a[i], b[j], acc[i][j], 0, 0, 0);
    }
  }
#pragma unroll
  for (int j = 0; j < 4; j++) {
    int col = colbase + wj * 64 + j * 16 + l15;
    float bj = bf2f(bias[col]);
#pragma unroll
    for (int i = 0; i < 4; i++) {
      int row0 = rowbase + wi * 64 + i * 16 + l4 * 4;
#pragma unroll
      for (int r = 0; r < 4; r++)
        out[(size_t)(row0 + r) * 512 + col] = f2bf((acc[i][j][r] + bj) * sc);
    }
  }
}

// ---------- flash attention: BM=128 (8 waves), BN=32, split-K=8 ----------
// v10 = v6 (best: counted-vmcnt single-barrier pipeline, 1 lockstep block/CU)
// + VALU diet ONLY (stagger refuted by v8/v9 A/B: both lost 18-28us vs v6):
//   * base-2 softmax: scale*log2e folded into Qp by k_proj; exp = raw
//     v_exp_f32; mask-apply is select-only (no mul); threshold 11.5 bits.
//   * deferred li: per-lane partials (alpha is 16-lane-group-uniform so the
//     rescale commutes); ONE dpp reduce in the epilogue instead of 32
//     dpp-adds per iteration.
// Everything else byte-identical to v6. Guards: FETCH ~67.4MB, WRITE
// ~94.7MB, VGPR 128 (any WRITE jump = spill = revert).
__global__ __launch_bounds__(512, 2) void k_attn(
    const unsigned short* __restrict__ Qp, const unsigned short* __restrict__ Kp,
    const unsigned short* __restrict__ Vt, const unsigned long long* __restrict__ mbits,
    unsigned short* __restrict__ Opart, float* __restrict__ mpart, float* __restrict__ lpart) {
  __shared__ alignas(16) unsigned short KB[2][16384];   // 2 x 32 k-rows x 512 (col-swizzled)
  __shared__ alignas(16) unsigned short VB[16384];      // 512 d-rows x 32 (chunk-swizzled)
  __shared__ alignas(16) unsigned short P2[2][4][128][8];  // 2 x [koct][q-row][8]
  __shared__ alignas(16) float alds[2][128];            // per-row rescale factor
  __shared__ alignas(16) int nfl[2][8];                 // per-wave rescale flags
  int tid = threadIdx.x, lane = tid & 63, wave = tid >> 6;
  int l15 = lane & 15, l4 = lane >> 4;
  int b = blockIdx.x;
  int split = b & 7;
  int qb = (b >> 3) * 128;

  short8 qf[16];  // persistent Q fragments: wave's 16 rows x 512
  {
    int row = qb + wave * 16 + l15;
#pragma unroll
    for (int t = 0; t < 16; t++)
      qf[t] = *(const short8*)(Qp + (size_t)row * 512 + t * 32 + l4 * 8);
  }
  f32x4 o[8][4];  // all 128 rows x wave's 64 d-cols
#pragma unroll
  for (int i = 0; i < 8; i++)
#pragma unroll
    for (int j = 0; j < 4; j++) o[i][j] = f32x4{0.f, 0.f, 0.f, 0.f};
  float mi[4] = {NEGF, NEGF, NEGF, NEGF};
  float li_l[4] = {0.f, 0.f, 0.f, 0.f};   // per-lane partial row sums

  int swK = l15 | ((l15 & 3) << 4);   // K read swizzle (matches deposit swz(row))
  const unsigned int* mb32 = (const unsigned int*)mbits;

  // prologue: stage K(0) -> KB[0], drain, sync
  {
    int tv = split * 32;
#pragma unroll
    for (int t = 0; t < 4; t++) {
      int r = wave * 4 + t;
      int swz = (r & 15) | ((r & 3) << 4);
      gl_lds16(Kp + (size_t)(tv * 32 + r) * 512 + ((lane ^ swz) * 8), &KB[0][r * 512]);
    }
  }
  __builtin_amdgcn_s_waitcnt(0x0F70);  // vmcnt(0)
  __builtin_amdgcn_s_barrier();

  for (int it = 0; it < 32; it++) {
    int cur = it & 1, prv = cur ^ 1;
    int tv = split * 32 + it;

    // 0. mask loads FIRST (oldest in VMEM FIFO)
    unsigned mw[4];
#pragma unroll
    for (int r = 0; r < 4; r++)
      mw[r] = mb32[((size_t)(qb + wave * 16 + l4 * 4 + r) * 128 + split * 16 + (it >> 1)) * 2 + (it & 1)];
    asm volatile("" ::: "memory");  // pin masks before the gl_lds issues

    // 1. issue K(it+1) -> KB[prv]
    {
      int tv1 = (it < 31) ? tv + 1 : tv;
#pragma unroll
      for (int t = 0; t < 4; t++) {
        int r = wave * 4 + t;
        int swz = (r & 15) | ((r & 3) << 4);
        gl_lds16(Kp + (size_t)(tv1 * 32 + r) * 512 + ((lane ^ swz) * 8), &KB[prv][r * 512]);
      }
    }

    // 2. PV(it-1): rescale + MFMA from P2[prv] / own VB quarter
    if (it) {
      __builtin_amdgcn_s_waitcnt(0x0F78);  // vmcnt(8): V(it-1) landed
      __builtin_amdgcn_sched_barrier(0);
      {
        const int4* n4 = (const int4*)&nfl[prv][0];
        int4 na = n4[0], nb4 = n4[1];
        if (na.x | na.y | na.z | na.w | nb4.x | nb4.y | nb4.z | nb4.w) {
#pragma unroll
          for (int rf = 0; rf < 8; rf++) {
            f32x4 av = *(const f32x4*)&alds[prv][rf * 16 + l4 * 4];
#pragma unroll
            for (int df = 0; df < 4; df++)
#pragma unroll
              for (int j = 0; j < 4; j++) o[rf][df][j] *= av[j];
          }
        }
      }
      short8 vf[4];
#pragma unroll
      for (int df = 0; df < 4; df++) {
        int d = wave * 64 + df * 16 + l15;
        vf[df] = *(const short8*)&VB[d * 32 + ((l4 ^ ((l15 >> 2) & 3)) * 8)];
      }
      __builtin_amdgcn_s_setprio(1);
#pragma unroll
      for (int rf = 0; rf < 8; rf++) {
        short8 pa = *(const short8*)&P2[prv][l4][rf * 16 + l15][0];
#pragma unroll
        for (int df = 0; df < 4; df++)
          o[rf][df] = __builtin_amdgcn_mfma_f32_16x16x32_bf16(pa, vf[df], o[rf][df], 0, 0, 0);
      }
      __builtin_amdgcn_s_setprio(0);
    }

    // 3. issue V(it) -> own VB quarter (wave-private; after our PV reads)
#pragma unroll
    for (int t = 0; t < 4; t++) {
      int inst = wave * 4 + t;             // 32 insts, 16 d-rows each
      int d = inst * 16 + (lane >> 2);
      int cg = (lane & 3) ^ ((d >> 2) & 3);
      gl_lds16(Vt + (size_t)tv * 16384 + d * 32 + cg * 8, &VB[inst * 512]);
    }

    // 4. S = Q K^T (128x32) from KB[cur] (Qp pre-scaled by SCALE_LOG2E)
    f32x4 sacc[2];
#pragma unroll
    for (int c = 0; c < 2; c++) sacc[c] = f32x4{0.f, 0.f, 0.f, 0.f};
    __builtin_amdgcn_s_setprio(1);
#pragma unroll
    for (int t2 = 0; t2 < 16; t2++) {
      short8 a = qf[t2];
#pragma unroll
      for (int c = 0; c < 2; c++) {
        int row = c * 16 + l15;
        short8 bb = *(const short8*)&KB[cur][row * 512 + (((t2 * 4 + l4) ^ swK) * 8)];
        sacc[c] = __builtin_amdgcn_mfma_f32_16x16x32_bf16(a, bb, sacc[c], 0, 0, 0);
      }
    }
    __builtin_amdgcn_s_setprio(0);

    // 5. mask (select-only; compiler wait here retires masks + old V, not fresh K/V)
#pragma unroll
    for (int c = 0; c < 2; c++)
#pragma unroll
      for (int r = 0; r < 4; r++) {
        bool msk = (mw[r] >> (c * 16 + l15)) & 1u;
        sacc[c][r] = msk ? NEGF : sacc[c][r];
      }

    // 6. deferred-max online softmax, base-2 (DPP reductions, VALU-only)
    float al4[4];
    bool need = false;
#pragma unroll
    for (int r = 0; r < 4; r++) {
      float t = dpp_fmax16(fmaxf(sacc[0][r], sacc[1][r]));
      al4[r] = t;
      need |= (t > mi[r] + 11.5f);
    }
    unsigned long long blt = __ballot(need);
    if (lane == 0) nfl[cur][wave] = (blt != 0ULL) ? 1 : 0;
    if (blt) {                          // wave-uniform cold path
#pragma unroll
      for (int r = 0; r < 4; r++) {
        float mn = fmaxf(mi[r], al4[r]);
        float a = exp2v(mi[r] - mn);
        li_l[r] *= a;
        mi[r] = mn;
        al4[r] = a;
      }
    } else {
#pragma unroll
      for (int r = 0; r < 4; r++) al4[r] = 1.0f;
    }
    if (l15 == 0) *(f32x4*)&alds[cur][wave * 16 + l4 * 4] = f32x4{al4[0], al4[1], al4[2], al4[3]};

#pragma unroll
    for (int r = 0; r < 4; r++) {
      sacc[0][r] = exp2v(sacc[0][r] - mi[r]);
      sacc[1][r] = exp2v(sacc[1][r] - mi[r]);
      li_l[r] += sacc[0][r] + sacc[1][r];   // per-lane partial; reduced in epilogue
    }

    // 7. P(it) -> P2[cur]
#pragma unroll
    for (int r = 0; r < 4; r++) {
      int prow = wave * 16 + l4 * 4 + r;
#pragma unroll
      for (int c = 0; c < 2; c++)
        P2[cur][c * 2 + (l15 >> 3)][prow][l15 & 7] = f2bf(sacc[c][r]);
    }

    // 8. single barrier: K(it+1) landed for all, P/alds visible; V(it) stays in flight
    __builtin_amdgcn_s_waitcnt(0x0074);  // vmcnt(4) lgkmcnt(0)
    __builtin_amdgcn_s_barrier();
  }

  // epilogue PV(31): buffers [1]
  __builtin_amdgcn_s_waitcnt(0x0F70);  // vmcnt(0): V(31) landed
  __builtin_amdgcn_sched_barrier(0);
  {
    const int4* n4 = (const int4*)&nfl[1][0];
    int4 na = n4[0], nb4 = n4[1];
    if (na.x | na.y | na.z | na.w | nb4.x | nb4.y | nb4.z | nb4.w) {
#pragma unroll
      for (int rf = 0; rf < 8; rf++) {
        f32x4 av = *(const f32x4*)&alds[1][rf * 16 + l4 * 4];
#pragma unroll
        for (int df = 0; df < 4; df++)
#pragma unroll
          for (int j = 0; j < 4; j++) o[rf][df][j] *= av[j];
      }
    }
    short8 vf[4];
#pragma unroll
    for (int df = 0; df < 4; df++) {
      int d = wave * 64 + df * 16 + l15;
      vf[df] = *(const short8*)&VB[d * 32 + ((l4 ^ ((l15 >> 2) & 3)) * 8)];
    }
#pragma unroll
    for (int rf = 0; rf < 8; rf++) {
      short8 pa = *(const short8*)&P2[1][l4][rf * 16 + l15][0];
#pragma unroll
      for (int df = 0; df < 4; df++)
        o[rf][df] = __builtin_amdgcn_mfma_f32_16x16x32_bf16(pa, vf[df], o[rf][df], 0, 0, 0);
    }
  }

  // ---- epilogue: reduce li, store m/l + fragment-layout bf16 partials ----
  float li[4];
#pragma unroll
  for (int r = 0; r < 4; r++) li[r] = dpp_fadd16(li_l[r]);
#pragma unroll
  for (int r = 0; r < 4; r++) {
    int row = qb + wave * 16 + l4 * 4 + r;
    if (l15 == 0) {
      mpart[(size_t)split * 8192 + row] = mi[r];
      lpart[(size_t)split * 8192 + row] = li[r];
    }
  }
  uint2* op2 = (uint2*)Opart;
#pragma unroll
  for (int rf = 0; rf < 8; rf++)
#pragma unroll
    for (int df = 0; df < 4; df++) {
      int f = wave * 4 + df;   // global 16-col d-frag index 0..31
      uint2 v;
      v.x = (unsigned)f2bf(o[rf][df][0]) | ((unsigned)f2bf(o[rf][df][1]) << 16);
      v.y = (unsigned)f2bf(o[rf][df][2]) | ((unsigned)f2bf(o[rf][df][3]) << 16);
      op2[(((size_t)b * 32 + f) * 8 + rf) * 64 + l4 * 16 + l15] = v;
    }
}

// ---------- combine 8 split-K partials (base-2 weights) -> f32 out ----------
// 256 blocks (quarter of the 32 d-frags each) so all CUs participate.
__global__ void k_combine(const unsigned short* __restrict__ Opart,
                          const float* __restrict__ mpart, const float* __restrict__ lpart,
                          float* __restrict__ out) {
  int q = blockIdx.x;                 // 0..63 (128-row tile)
  int quarter = blockIdx.y;           // 0..3
  int tid = threadIdx.x;              // 512 threads
  int wave = tid >> 6, lane = tid & 63, l4 = (lane >> 4) & 3, l15 = lane & 15;
  int row0 = q * 128 + wave * 16 + l4 * 4;

  float w[8][4], inv[4];
#pragma unroll
  for (int r = 0; r < 4; r++) {
    float M = NEGF;
    float mv[8];
#pragma unroll
    for (int s = 0; s < 8; s++) { mv[s] = mpart[s * 8192 + row0 + r]; M = fmaxf(M, mv[s]); }
    float L = 0.f;
#pragma unroll
    for (int s = 0; s < 8; s++) {
      float ws = exp2v(mv[s] - M);    // log2-domain partial maxima
      w[s][r] = ws;
      L += ws * lpart[s * 8192 + row0 + r];
    }
    inv[r] = 1.0f / L;
  }
  const uint2* op2 = (const uint2*)Opart;
#pragma unroll
  for (int fo = 0; fo < 8; fo++) {
    int f = quarter * 8 + fo;
    float acc[4] = {0.f, 0.f, 0.f, 0.f};
#pragma unroll
    for (int s = 0; s < 8; s++) {
      uint2 v = op2[(((size_t)(q * 8 + s) * 32 + f) * 8 + wave) * 64 + l4 * 16 + l15];
      acc[0] += w[s][0] * bf2f((unsigned short)(v.x & 0xFFFFu));
      acc[1] += w[s][1] * bf2f((unsigned short)(v.x >> 16));
      acc[2] += w[s][2] * bf2f((unsigned short)(v.y & 0xFFFFu));
      acc[3] += w[s][3] * bf2f((unsigned short)(v.y >> 16));
    }
    int col = f * 16 + l15;
#pragma unroll
    for (int r = 0; r < 4; r++)
      out[(size_t)(row0 + r) * 512 + col] = acc[r] * inv[r];
  }
}

extern "C" void kernel_launch(void* const* d_in, const int* in_sizes, int n_in,
                              void* d_out, int out_size, void* d_ws, size_t ws_size,
                              hipStream_t stream) {
  const void* Q   = d_in[0];
  const void* K   = d_in[1];
  const void* V   = d_in[2];
  const void* WQw = d_in[3];
  const void* WQb = d_in[4];
  const void* WKw = d_in[5];
  const void* WKb = d_in[6];
  const void* mask = d_in[7];
  float* out = (float*)d_out;
  char* ws = (char*)d_ws;
  (void)in_sizes; (void)n_in; (void)out_size; (void)ws_size;

  constexpr size_t SZ_MAT = (size_t)8192 * 512 * 2;  // 8 MB bf16
  size_t off = 4096;
  unsigned short* Qb  = (unsigned short*)(ws + off); off += SZ_MAT;
  unsigned short* Kb  = (unsigned short*)(ws + off); off += SZ_MAT;
  unsigned short* Wqb = (unsigned short*)(ws + off); off += (size_t)512 * 512 * 2;
  unsigned short* Wkb = (unsigned short*)(ws + off); off += (size_t)512 * 512 * 2;
  unsigned short* bqb = (unsigned short*)(ws + off); off += 1024;
  unsigned short* bkb = (unsigned short*)(ws + off); off += 1024;
  unsigned short* Vt  = (unsigned short*)(ws + off); off += SZ_MAT;
  unsigned short* Qp  = (unsigned short*)(ws + off); off += SZ_MAT;
  unsigned short* Kp  = (unsigned short*)(ws + off); off += SZ_MAT;
  unsigned long long* mbits = (unsigned long long*)(ws + off); off += (size_t)8192 * 128 * 8;
  unsigned short* Opart = (unsigned short*)(ws + off); off += (size_t)512 * 512 * 32 * 8;  // 64 MB
  float* mpart = (float*)(ws + off); off += (size_t)8 * 8192 * 4;
  float* lpart = (float*)(ws + off); off += (size_t)8 * 8192 * 4;
  int* fflag = (int*)ws;
  int* esize = (int*)(ws + 64);

  k_detect<<<2, 64, 0, stream>>>((const unsigned int*)Q, (const unsigned int*)mask, fflag, esize);
  k_prep<<<4354, 256, 0, stream>>>(Q, Qb, K, Kb, WQw, Wqb, WKw, Wkb, WQb, bqb, WKb, bkb, fflag);
  k_transpose_v<<<dim3(128, 8), 256, 0, stream>>>(V, fflag, Vt);
  k_pack<<<1024, 256, 0, stream>>>(mask, esize, mbits);
  k_proj<<<dim3(64, 4, 2), 256, 0, stream>>>(Qb, Wqb, bqb, Qp, Kb, Wkb, bkb, Kp);
  k_attn<<<512, 512, 0, stream>>>(Qp, Kp, Vt, mbits, Opart, mpart, lpart);
  k_combine<<<dim3(64, 4), 512, 0, stream>>>(Opart, mpart, lpart, out);
}

// Round 10
// 749.384 us; speedup vs baseline: 1.1610x; 1.0388x over previous
//
#include <hip/hip_runtime.h>

typedef __attribute__((ext_vector_type(8))) short short8;
typedef __attribute__((ext_vector_type(4))) float f32x4;

#define DEVFN __device__ __forceinline__

constexpr float NEGF = -4294967296.0f;              // -(1<<32)
// 1/sqrt(512) * log2(e): folded into Qp by k_proj; k_attn softmax runs base-2.
constexpr float SCALE_LOG2E = 0.06375872465057373f;

DEVFN unsigned short f2bf(float f) {
  unsigned int u = __float_as_uint(f);
  u += 0x7FFFu + ((u >> 16) & 1u);   // RNE (inputs finite)
  return (unsigned short)(u >> 16);
}
DEVFN float bf2f(unsigned short h) { return __uint_as_float((unsigned)h << 16); }

DEVFN float exp2v(float x) {  // raw v_exp_f32: D = 2^S0 (no log2e mul)
  float r;
  asm("v_exp_f32 %0, %1" : "=v"(r) : "v"(x));
  return r;
}

DEVFN void gl_lds16(const void* g, void* l) {
  __builtin_amdgcn_global_load_lds(
      (const __attribute__((address_space(1))) unsigned int*)g,
      (__attribute__((address_space(3))) unsigned int*)l, 16, 0, 0);
}

// 16-lane butterfly reductions on the VALU (DPP) instead of ds_swizzle (LDS pipe).
DEVFN float dpp_fmax16(float x) {
  int v;
  v = __builtin_amdgcn_update_dpp(0, __float_as_int(x), 0xB1, 0xF, 0xF, true);
  x = fmaxf(x, __int_as_float(v));
  v = __builtin_amdgcn_update_dpp(0, __float_as_int(x), 0x4E, 0xF, 0xF, true);
  x = fmaxf(x, __int_as_float(v));
  v = __builtin_amdgcn_update_dpp(0, __float_as_int(x), 0x141, 0xF, 0xF, true);
  x = fmaxf(x, __int_as_float(v));
  v = __builtin_amdgcn_update_dpp(0, __float_as_int(x), 0x140, 0xF, 0xF, true);
  x = fmaxf(x, __int_as_float(v));
  return x;
}
DEVFN float dpp_fadd16(float x) {
  int v;
  v = __builtin_amdgcn_update_dpp(0, __float_as_int(x), 0xB1, 0xF, 0xF, true);
  x += __int_as_float(v);
  v = __builtin_amdgcn_update_dpp(0, __float_as_int(x), 0x4E, 0xF, 0xF, true);
  x += __int_as_float(v);
  v = __builtin_amdgcn_update_dpp(0, __float_as_int(x), 0x141, 0xF, 0xF, true);
  x += __int_as_float(v);
  v = __builtin_amdgcn_update_dpp(0, __float_as_int(x), 0x140, 0xF, 0xF, true);
  x += __int_as_float(v);
  return x;
}

// ---------- merged detectors: block 0 = Q dtype, block 1 = mask esize ----------
__global__ void k_detect(const unsigned int* __restrict__ q, const unsigned int* __restrict__ m,
                         int* __restrict__ fflag, int* __restrict__ esize) {
  int lane = threadIdx.x;
  if (blockIdx.x == 0) {
    unsigned bad = 0;
    for (int i = 0; i < 64; i++) {
      unsigned v = q[i * 64 + lane];
      unsigned h = v & 0xFFFFu;
      unsigned e = (h >> 7) & 0xFFu;
      if (h != 0u && (e < 96u || e > 150u)) bad = 1;
    }
    unsigned long long anyb = __ballot(bad != 0);
    if (lane == 0) *fflag = (anyb == 0ULL) ? 1 : 0;
  } else {
    unsigned okd = 1, okh = 1, okb = 1;
    for (int i = 0; i < 64; i++) {
      unsigned v = m[i * 64 + lane];
      if (v > 1u && v != 0x3F800000u) okd = 0;   // int32/f32 0|1|1.0f
      unsigned h0 = v & 0xFFFFu, h1 = v >> 16;
      if ((h0 && h0 != 0x3F80u && h0 != 1u) || (h1 && h1 != 0x3F80u && h1 != 1u)) okh = 0;
      if (v & 0xFEFEFEFEu) okb = 0;
    }
    okd = (__ballot(okd == 0) == 0ULL);
    okh = (__ballot(okh == 0) == 0ULL);
    okb = (__ballot(okb == 0) == 0ULL);
    if (lane == 0) *esize = okd ? 4 : (okh ? 2 : 1);
  }
}

// ---------- fused convert-or-copy -> bf16 for Q,K,WQw,WKw,bq,bk ----------
__global__ void k_prep(const void* __restrict__ Q, unsigned short* __restrict__ Qb,
                       const void* __restrict__ K, unsigned short* __restrict__ Kb,
                       const void* __restrict__ Wq, unsigned short* __restrict__ Wqb,
                       const void* __restrict__ Wk, unsigned short* __restrict__ Wkb,
                       const void* __restrict__ bq, unsigned short* __restrict__ bqb,
                       const void* __restrict__ bk, unsigned short* __restrict__ bkb,
                       const int* __restrict__ bf16flag) {
  int blk = blockIdx.x;
  const void* src; unsigned short* dst; int base, n;
  if (blk < 2048)      { src = Q;  dst = Qb;  base = blk;        n = 8192 * 512; }
  else if (blk < 4096) { src = K;  dst = Kb;  base = blk - 2048; n = 8192 * 512; }
  else if (blk < 4224) { src = Wq; dst = Wqb; base = blk - 4096; n = 512 * 512; }
  else if (blk < 4352) { src = Wk; dst = Wkb; base = blk - 4224; n = 512 * 512; }
  else if (blk == 4352){ src = bq; dst = bqb; base = 0;          n = 512; }
  else                 { src = bk; dst = bkb; base = 0;          n = 512; }
  int i = (base * 256 + threadIdx.x) * 8;
  if (i >= n) return;
  if (*bf16flag) {
    *(uint4*)(dst + i) = *(const uint4*)((const unsigned short*)src + i);
  } else {
    const float* f = (const float*)src + i;
    float4 a = *(const float4*)f, b = *(const float4*)(f + 4);
    uint4 o;
    o.x = (unsigned)f2bf(a.x) | ((unsigned)f2bf(a.y) << 16);
    o.y = (unsigned)f2bf(a.z) | ((unsigned)f2bf(a.w) << 16);
    o.z = (unsigned)f2bf(b.x) | ((unsigned)f2bf(b.y) << 16);
    o.w = (unsigned)f2bf(b.z) | ((unsigned)f2bf(b.w) << 16);
    *(uint4*)(dst + i) = o;
  }
}

// ---------- V [8192x512] -> tiled V^T: Vt[t][d][c], tiles of 32 k-rows ----------
__global__ void k_transpose_v(const void* __restrict__ Vsrc, const int* __restrict__ bf16flag,
                              unsigned short* __restrict__ Vt) {
  __shared__ unsigned short T[64][72];
  int t = threadIdx.x;
  int rb = blockIdx.x, cb = blockIdx.y;
  int r = t >> 3, c8 = (t & 7) * 8;
  int isbf = *bf16flag;
#pragma unroll
  for (int j = 0; j < 2; j++) {
    int row = rb * 64 + j * 32 + r;
    unsigned short e[8];
    if (isbf) {
      alignas(16) unsigned short tmp[8];
      *(uint4*)tmp = *(const uint4*)((const unsigned short*)Vsrc + (size_t)row * 512 + cb * 64 + c8);
#pragma unroll
      for (int i = 0; i < 8; i++) e[i] = tmp[i];
    } else {
      const float* f = (const float*)Vsrc + (size_t)row * 512 + cb * 64 + c8;
      float4 a = *(const float4*)f, b = *(const float4*)(f + 4);
      e[0] = f2bf(a.x); e[1] = f2bf(a.y); e[2] = f2bf(a.z); e[3] = f2bf(a.w);
      e[4] = f2bf(b.x); e[5] = f2bf(b.y); e[6] = f2bf(b.z); e[7] = f2bf(b.w);
    }
#pragma unroll
    for (int i = 0; i < 8; i++) T[c8 + i][j * 32 + r] = e[i];
  }
  __syncthreads();
#pragma unroll
  for (int j = 0; j < 2; j++) {
    int d = cb * 64 + j * 32 + r;                   // V col = V^T row
    alignas(16) unsigned short o[8];
#pragma unroll
    for (int i = 0; i < 8; i++) o[i] = T[j * 32 + r][c8 + i];
    int tt = rb * 2 + (c8 >> 5);
    *(uint4*)(Vt + ((size_t)tt * 512 + d) * 32 + (c8 & 31)) = *(const uint4*)o;
  }
}

// ---------- mask -> bit-packed row-major [8192][128] uint64 ----------
DEVFN unsigned nib4(unsigned v) {
  unsigned t = v; t |= t >> 1; t |= t >> 2; t |= t >> 4; t &= 0x01010101u;
  return (t * 0x10204080u) >> 28;
}
DEVFN unsigned pair2(unsigned v) {
  unsigned t = v; t |= t >> 8; t |= t >> 4; t |= t >> 2; t |= t >> 1;
  return (t & 1u) | (((t >> 16) & 1u) << 1);
}
__global__ void k_pack(const void* __restrict__ mask, const int* __restrict__ esize,
                       unsigned long long* __restrict__ bits) {
  int wv = (blockIdx.x * blockDim.x + threadIdx.x) >> 6;  // 4096 waves
  int lane = threadIdx.x & 63;
  int sz = *esize;
  if (sz == 4) {
    const unsigned int* m = (const unsigned int*)mask;
    for (int g = wv; g < 262144; g += 4096) {
      size_t base = (size_t)g * 256 + lane;
      unsigned v0 = m[base], v1 = m[base + 64], v2 = m[base + 128], v3 = m[base + 192];
      unsigned long long b0 = __ballot(v0 != 0u);
      unsigned long long b1 = __ballot(v1 != 0u);
      unsigned long long b2 = __ballot(v2 != 0u);
      unsigned long long b3 = __ballot(v3 != 0u);
      if (lane == 0) {
        bits[g * 4 + 0] = b0; bits[g * 4 + 1] = b1;
        bits[g * 4 + 2] = b2; bits[g * 4 + 3] = b3;
      }
    }
  } else if (sz == 2) {
    const uint4* m = (const uint4*)mask;
    for (int g = wv; g < 131072; g += 4096) {
      uint4 v = m[(size_t)g * 64 + lane];
      unsigned c8 = pair2(v.x) | (pair2(v.y) << 2) | (pair2(v.z) << 4) | (pair2(v.w) << 6);
      unsigned long long x = (unsigned long long)c8 << ((lane & 7) * 8);
      x |= __shfl_xor(x, 1); x |= __shfl_xor(x, 2); x |= __shfl_xor(x, 4);
      if ((lane & 7) == 0) bits[g * 8 + (lane >> 3)] = x;
    }
  } else {
    const uint4* m = (const uint4*)mask;
    for (int g = wv; g < 65536; g += 4096) {
      uint4 v = m[(size_t)g * 64 + lane];
      unsigned c16 = nib4(v.x) | (nib4(v.y) << 4) | (nib4(v.z) << 8) | (nib4(v.w) << 12);
      unsigned long long x = (unsigned long long)c16 << ((lane & 3) * 16);
      x |= __shfl_xor(x, 1); x |= __shfl_xor(x, 2);
      if ((lane & 3) == 0) bits[g * 16 + (lane >> 2)] = x;
    }
  }
}

// ---------- fused proj GEMM (z=0: Q, z=1: K): out = (A @ W^T + bias)*sc, bf16 ----------
// z=0 (Q side) folds SCALE_LOG2E so k_attn's softmax runs in base-2 with no muls.
__global__ __launch_bounds__(256, 2) void k_proj(
    const unsigned short* __restrict__ Aq, const unsigned short* __restrict__ Wq,
    const unsigned short* __restrict__ bq, unsigned short* __restrict__ outq,
    const unsigned short* __restrict__ Ak, const unsigned short* __restrict__ Wk,
    const unsigned short* __restrict__ bk, unsigned short* __restrict__ outk) {
  const unsigned short* A = blockIdx.z ? Ak : Aq;
  const unsigned short* W = blockIdx.z ? Wk : Wq;
  const unsigned short* bias = blockIdx.z ? bk : bq;
  unsigned short* out = blockIdx.z ? outk : outq;
  float sc = blockIdx.z ? 1.0f : SCALE_LOG2E;

  __shared__ alignas(16) unsigned short As[128 * 64];
  __shared__ alignas(16) unsigned short Bs[128 * 64];
  int tid = threadIdx.x, lane = tid & 63, wave = tid >> 6;
  int wi = wave >> 1, wj = wave & 1;
  int l15 = lane & 15, l4 = lane >> 4;
  int rowbase = blockIdx.x * 128, colbase = blockIdx.y * 128;
  f32x4 acc[4][4];
#pragma unroll
  for (int i = 0; i < 4; i++)
#pragma unroll
    for (int j = 0; j < 4; j++) acc[i][j] = f32x4{0.f, 0.f, 0.f, 0.f};

  int swr = l15 & 7;
  for (int kb = 0; kb < 512; kb += 64) {
    __syncthreads();
#pragma unroll
    for (int t = 0; t < 4; t++) {
      int inst = wave * 4 + t;
      int r = inst * 8 + (lane >> 3);
      int c = ((lane & 7) ^ (r & 7)) * 8;
      gl_lds16(A + (size_t)(rowbase + r) * 512 + kb + c, &As[inst * 512]);
      gl_lds16(W + (size_t)(colbase + r) * 512 + kb + c, &Bs[inst * 512]);
    }
    __syncthreads();
#pragma unroll
    for (int t2 = 0; t2 < 2; t2++) {
      short8 a[4], b[4];
#pragma unroll
      for (int i = 0; i < 4; i++) {
        int row = wi * 64 + i * 16 + l15;
        a[i] = *(const short8*)&As[row * 64 + (((t2 * 4 + l4) ^ swr) * 8)];
      }
#pragma unroll
      for (int j = 0; j < 4; j++) {
        int row = wj * 64 + j * 16 + l15;
        b[j] = *(const short8*)&Bs[row * 64 + (((t2 * 4 + l4) ^ swr) * 8)];
      }
#pragma unroll
      for (int i = 0; i < 4; i++)
#pragma unroll
        for (int j = 0; j < 4; j++)
          acc[i][j] = __builtin_amdgcn_mfma_f32_16x16x32_bf16(a[i], b[j], acc[i][j], 0, 0, 0);
    }
  }
#pragma unroll
  for (int j = 0; j < 4; j++) {
    int col = colbase + wj * 64 + j * 16 + l15;
    float bj = bf2f(bias[col]);
#pragma unroll
    for (int i = 0; i < 4; i++) {
      int row0 = rowbase + wi * 64 + i * 16 + l4 * 4;
#pragma unroll
      for (int r = 0; r < 4; r++)
        out[(size_t)(row0 + r) * 512 + col] = f2bf((acc[i][j][r] + bj) * sc);
    }
  }
}

// ---------- flash attention: BM=128 (8 waves), BN=32, split-K=4, single round ----------
// v11 = v10 + VB double-buffer + splits=4:
//   * VB[2]: V(it+1) staged at END of iter it -> PV(it-1) reads data issued a
//     full iteration (~3.5K cyc) ago. The per-iter vmcnt(8) V-wait (an
//     L2-latency stall every iteration) is GONE. VB quarters are wave-private
//     for read AND write, so same-wave program order covers reuse; the
//     mask-apply's compiler vmcnt already retires V(it) each iteration.
//   * splits=4 -> 256 blocks = 1 lockstep block/CU in ONE round (v4/v5 showed
//     thrash comes from DRIFTING 2-blocks/CU, not split width; active set per
//     iter is 64KB regardless). One prologue/epilogue instead of two; Opart
//     halves to 32MB.
// Waits per iter: only the barrier's vmcnt(4) lgkm(0) (retires K(it+1), lets
// V(it+1) fly) -- every load is consumed >=2000 cycles after issue.
// LDS: KB 2x32KB + VB 2x32KB + P2 2x8KB + alds/nfl ~1.1KB = ~145KB, 1 block/CU.
// Guards: FETCH ~67MB (if >>100MB geometry theory wrong -> revert splits=8),
// WRITE ~63MB, VGPR 128.
__global__ __launch_bounds__(512, 2) void k_attn(
    const unsigned short* __restrict__ Qp, const unsigned short* __restrict__ Kp,
    const unsigned short* __restrict__ Vt, const unsigned long long* __restrict__ mbits,
    unsigned short* __restrict__ Opart, float* __restrict__ mpart, float* __restrict__ lpart) {
  __shared__ alignas(16) unsigned short KB[2][16384];   // 2 x 32 k-rows x 512 (col-swizzled)
  __shared__ alignas(16) unsigned short VB[2][16384];   // 2 x 512 d-rows x 32 (chunk-swizzled)
  __shared__ alignas(16) unsigned short P2[2][4][128][8];  // 2 x [koct][q-row][8]
  __shared__ alignas(16) float alds[2][128];            // per-row rescale factor
  __shared__ alignas(16) int nfl[2][8];                 // per-wave rescale flags
  int tid = threadIdx.x, lane = tid & 63, wave = tid >> 6;
  int l15 = lane & 15, l4 = lane >> 4;
  int b = blockIdx.x;
  int split = b & 3;                  // 4 splits x 2048 k-cols; XCD b%8 -> single split/XCD
  int qb = (b >> 2) * 128;            // 64 q-tiles of 128 rows

  short8 qf[16];  // persistent Q fragments: wave's 16 rows x 512
  {
    int row = qb + wave * 16 + l15;
#pragma unroll
    for (int t = 0; t < 16; t++)
      qf[t] = *(const short8*)(Qp + (size_t)row * 512 + t * 32 + l4 * 8);
  }
  f32x4 o[8][4];  // all 128 rows x wave's 64 d-cols
#pragma unroll
  for (int i = 0; i < 8; i++)
#pragma unroll
    for (int j = 0; j < 4; j++) o[i][j] = f32x4{0.f, 0.f, 0.f, 0.f};
  float mi[4] = {NEGF, NEGF, NEGF, NEGF};
  float li_l[4] = {0.f, 0.f, 0.f, 0.f};   // per-lane partial row sums

  int swK = l15 | ((l15 & 3) << 4);   // K read swizzle (matches deposit swz(row))
  const unsigned int* mb32 = (const unsigned int*)mbits;

#define STAGE_K(TV, BUF)                                                         \
  {                                                                              \
    _Pragma("unroll") for (int t = 0; t < 4; t++) {                              \
      int r = wave * 4 + t;                                                      \
      int swz = (r & 15) | ((r & 3) << 4);                                       \
      gl_lds16(Kp + (size_t)((TV) * 32 + r) * 512 + ((lane ^ swz) * 8),          \
               &KB[BUF][r * 512]);                                               \
    }                                                                            \
  }
#define STAGE_V(TV, BUF)                                                         \
  {                                                                              \
    _Pragma("unroll") for (int t = 0; t < 4; t++) {                              \
      int inst = wave * 4 + t;                                                   \
      int d = inst * 16 + (lane >> 2);                                           \
      int cg = (lane & 3) ^ ((d >> 2) & 3);                                      \
      gl_lds16(Vt + (size_t)(TV) * 16384 + d * 32 + cg * 8, &VB[BUF][inst * 512]); \
    }                                                                            \
  }

  // prologue: stage K(0)->KB[0] and V(0)->VB[0], drain, sync
  STAGE_K(split * 64, 0);
  STAGE_V(split * 64, 0);
  __builtin_amdgcn_s_waitcnt(0x0F70);  // vmcnt(0)
  __builtin_amdgcn_s_barrier();

  for (int it = 0; it < 64; it++) {
    int cur = it & 1, prv = cur ^ 1;
    int tv = split * 64 + it;

    // 0. mask loads FIRST (their compiler wait also retires V(it) as a side effect)
    unsigned mw[4];
#pragma unroll
    for (int r = 0; r < 4; r++)
      mw[r] = mb32[((size_t)(qb + wave * 16 + l4 * 4 + r) * 128 + split * 32 + (it >> 1)) * 2 + (it & 1)];
    asm volatile("" ::: "memory");  // pin masks before the gl_lds issues

    // 1. issue K(it+1) -> KB[prv]
    {
      int tv1 = (it < 63) ? tv + 1 : tv;
      STAGE_K(tv1, prv);
    }

    // 2. PV(it-1): rescale + MFMA from P2[prv] / VB[prv] -- NO vmcnt fence:
    //    V(it-1) was issued at iter it-2's end and retired by iter it-1's waits.
    if (it) {
      __builtin_amdgcn_sched_barrier(0);
      {
        const int4* n4 = (const int4*)&nfl[prv][0];
        int4 na = n4[0], nb4 = n4[1];
        if (na.x | na.y | na.z | na.w | nb4.x | nb4.y | nb4.z | nb4.w) {
#pragma unroll
          for (int rf = 0; rf < 8; rf++) {
            f32x4 av = *(const f32x4*)&alds[prv][rf * 16 + l4 * 4];
#pragma unroll
            for (int df = 0; df < 4; df++)
#pragma unroll
              for (int j = 0; j < 4; j++) o[rf][df][j] *= av[j];
          }
        }
      }
      short8 vf[4];
#pragma unroll
      for (int df = 0; df < 4; df++) {
        int d = wave * 64 + df * 16 + l15;
        vf[df] = *(const short8*)&VB[prv][d * 32 + ((l4 ^ ((l15 >> 2) & 3)) * 8)];
      }
      __builtin_amdgcn_s_setprio(1);
#pragma unroll
      for (int rf = 0; rf < 8; rf++) {
        short8 pa = *(const short8*)&P2[prv][l4][rf * 16 + l15][0];
#pragma unroll
        for (int df = 0; df < 4; df++)
          o[rf][df] = __builtin_amdgcn_mfma_f32_16x16x32_bf16(pa, vf[df], o[rf][df], 0, 0, 0);
      }
      __builtin_amdgcn_s_setprio(0);
    }

    // 3. S = Q K^T (128x32) from KB[cur] (Qp pre-scaled by SCALE_LOG2E)
    f32x4 sacc[2];
#pragma unroll
    for (int c = 0; c < 2; c++) sacc[c] = f32x4{0.f, 0.f, 0.f, 0.f};
    __builtin_amdgcn_s_setprio(1);
#pragma unroll
    for (int t2 = 0; t2 < 16; t2++) {
      short8 a = qf[t2];
#pragma unroll
      for (int c = 0; c < 2; c++) {
        int row = c * 16 + l15;
        short8 bb = *(const short8*)&KB[cur][row * 512 + (((t2 * 4 + l4) ^ swK) * 8)];
        sacc[c] = __builtin_amdgcn_mfma_f32_16x16x32_bf16(a, bb, sacc[c], 0, 0, 0);
      }
    }
    __builtin_amdgcn_s_setprio(0);

    // 4. mask (select-only; compiler wait retires masks + V(it), K(it+1) flies)
#pragma unroll
    for (int c = 0; c < 2; c++)
#pragma unroll
      for (int r = 0; r < 4; r++) {
        bool msk = (mw[r] >> (c * 16 + l15)) & 1u;
        sacc[c][r] = msk ? NEGF : sacc[c][r];
      }

    // 5. deferred-max online softmax, base-2 (DPP reductions, VALU-only)
    float al4[4];
    bool need = false;
#pragma unroll
    for (int r = 0; r < 4; r++) {
      float t = dpp_fmax16(fmaxf(sacc[0][r], sacc[1][r]));
      al4[r] = t;
      need |= (t > mi[r] + 11.5f);
    }
    unsigned long long blt = __ballot(need);
    if (lane == 0) nfl[cur][wave] = (blt != 0ULL) ? 1 : 0;
    if (blt) {                          // wave-uniform cold path
#pragma unroll
      for (int r = 0; r < 4; r++) {
        float mn = fmaxf(mi[r], al4[r]);
        float a = exp2v(mi[r] - mn);
        li_l[r] *= a;
        mi[r] = mn;
        al4[r] = a;
      }
    } else {
#pragma unroll
      for (int r = 0; r < 4; r++) al4[r] = 1.0f;
    }
    if (l15 == 0) *(f32x4*)&alds[cur][wave * 16 + l4 * 4] = f32x4{al4[0], al4[1], al4[2], al4[3]};

#pragma unroll
    for (int r = 0; r < 4; r++) {
      sacc[0][r] = exp2v(sacc[0][r] - mi[r]);
      sacc[1][r] = exp2v(sacc[1][r] - mi[r]);
      li_l[r] += sacc[0][r] + sacc[1][r];   // per-lane partial; reduced in epilogue
    }

    // 6. P(it) -> P2[cur]
#pragma unroll
    for (int r = 0; r < 4; r++) {
      int prow = wave * 16 + l4 * 4 + r;
#pragma unroll
      for (int c = 0; c < 2; c++)
        P2[cur][c * 2 + (l15 >> 3)][prow][l15 & 7] = f2bf(sacc[c][r]);
    }

    // 7. issue V(it+1) -> VB[prv] ((it+1)&1 == prv; this wave's quarter was
    //    already consumed by PV above -- wave-private, program-ordered)
    {
      int tvv = (it < 63) ? tv + 1 : tv;
      STAGE_V(tvv, prv);
    }

    // 8. single barrier: K(it+1) landed for all, P/alds visible; V(it+1) flies
    __builtin_amdgcn_s_waitcnt(0x0074);  // vmcnt(4) lgkmcnt(0)
    __builtin_amdgcn_s_barrier();
  }

  // epilogue PV(63): P2[1], VB[1] (V(63) staged at iter 62, long landed)
  __builtin_amdgcn_s_waitcnt(0x0F70);  // vmcnt(0): drain the tail restage
  __builtin_amdgcn_sched_barrier(0);
  {
    const int4* n4 = (const int4*)&nfl[1][0];
    int4 na = n4[0], nb4 = n4[1];
    if (na.x | na.y | na.z | na.w | nb4.x | nb4.y | nb4.z | nb4.w) {
#pragma unroll
      for (int rf = 0; rf < 8; rf++) {
        f32x4 av = *(const f32x4*)&alds[1][rf * 16 + l4 * 4];
#pragma unroll
        for (int df = 0; df < 4; df++)
#pragma unroll
          for (int j = 0; j < 4; j++) o[rf][df][j] *= av[j];
      }
    }
    short8 vf[4];
#pragma unroll
    for (int df = 0; df < 4; df++) {
      int d = wave * 64 + df * 16 + l15;
      vf[df] = *(const short8*)&VB[1][d * 32 + ((l4 ^ ((l15 >> 2) & 3)) * 8)];
    }
#pragma unroll
    for (int rf = 0; rf < 8; rf++) {
      short8 pa = *(const short8*)&P2[1][l4][rf * 16 + l15][0];
#pragma unroll
      for (int df = 0; df < 4; df++)
        o[rf][df] = __builtin_amdgcn_mfma_f32_16x16x32_bf16(pa, vf[df], o[rf][df], 0, 0, 0);
    }
  }

  // ---- epilogue: reduce li, store m/l + fragment-layout bf16 partials ----
  float li[4];
#pragma unroll
  for (int r = 0; r < 4; r++) li[r] = dpp_fadd16(li_l[r]);
#pragma unroll
  for (int r = 0; r < 4; r++) {
    int row = qb + wave * 16 + l4 * 4 + r;
    if (l15 == 0) {
      mpart[(size_t)split * 8192 + row] = mi[r];
      lpart[(size_t)split * 8192 + row] = li[r];
    }
  }
  uint2* op2 = (uint2*)Opart;
#pragma unroll
  for (int rf = 0; rf < 8; rf++)
#pragma unroll
    for (int df = 0; df < 4; df++) {
      int f = wave * 4 + df;   // global 16-col d-frag index 0..31
      uint2 v;
      v.x = (unsigned)f2bf(o[rf][df][0]) | ((unsigned)f2bf(o[rf][df][1]) << 16);
      v.y = (unsigned)f2bf(o[rf][df][2]) | ((unsigned)f2bf(o[rf][df][3]) << 16);
      op2[(((size_t)b * 32 + f) * 8 + rf) * 64 + l4 * 16 + l15] = v;
    }
#undef STAGE_K
#undef STAGE_V
}

// ---------- combine 4 split-K partials (base-2 weights) -> f32 out ----------
__global__ void k_combine(const unsigned short* __restrict__ Opart,
                          const float* __restrict__ mpart, const float* __restrict__ lpart,
                          float* __restrict__ out) {
  int q = blockIdx.x;                 // 0..63 (128-row tile)
  int quarter = blockIdx.y;           // 0..3
  int tid = threadIdx.x;              // 512 threads
  int wave = tid >> 6, lane = tid & 63, l4 = (lane >> 4) & 3, l15 = lane & 15;
  int row0 = q * 128 + wave * 16 + l4 * 4;

  float w[4][4], inv[4];
#pragma unroll
  for (int r = 0; r < 4; r++) {
    float M = NEGF;
    float mv[4];
#pragma unroll
    for (int s = 0; s < 4; s++) { mv[s] = mpart[s * 8192 + row0 + r]; M = fmaxf(M, mv[s]); }
    float L = 0.f;
#pragma unroll
    for (int s = 0; s < 4; s++) {
      float ws = exp2v(mv[s] - M);    // log2-domain partial maxima
      w[s][r] = ws;
      L += ws * lpart[s * 8192 + row0 + r];
    }
    inv[r] = 1.0f / L;
  }
  const uint2* op2 = (const uint2*)Opart;
#pragma unroll
  for (int fo = 0; fo < 8; fo++) {
    int f = quarter * 8 + fo;
    float acc[4] = {0.f, 0.f, 0.f, 0.f};
#pragma unroll
    for (int s = 0; s < 4; s++) {
      uint2 v = op2[(((size_t)(q * 4 + s) * 32 + f) * 8 + wave) * 64 + l4 * 16 + l15];
      acc[0] += w[s][0] * bf2f((unsigned short)(v.x & 0xFFFFu));
      acc[1] += w[s][1] * bf2f((unsigned short)(v.x >> 16));
      acc[2] += w[s][2] * bf2f((unsigned short)(v.y & 0xFFFFu));
      acc[3] += w[s][3] * bf2f((unsigned short)(v.y >> 16));
    }
    int col = f * 16 + l15;
#pragma unroll
    for (int r = 0; r < 4; r++)
      out[(size_t)(row0 + r) * 512 + col] = acc[r] * inv[r];
  }
}

extern "C" void kernel_launch(void* const* d_in, const int* in_sizes, int n_in,
                              void* d_out, int out_size, void* d_ws, size_t ws_size,
                              hipStream_t stream) {
  const void* Q   = d_in[0];
  const void* K   = d_in[1];
  const void* V   = d_in[2];
  const void* WQw = d_in[3];
  const void* WQb = d_in[4];
  const void* WKw = d_in[5];
  const void* WKb = d_in[6];
  const void* mask = d_in[7];
  float* out = (float*)d_out;
  char* ws = (char*)d_ws;
  (void)in_sizes; (void)n_in; (void)out_size; (void)ws_size;

  constexpr size_t SZ_MAT = (size_t)8192 * 512 * 2;  // 8 MB bf16
  size_t off = 4096;
  unsigned short* Qb  = (unsigned short*)(ws + off); off += SZ_MAT;
  unsigned short* Kb  = (unsigned short*)(ws + off); off += SZ_MAT;
  unsigned short* Wqb = (unsigned short*)(ws + off); off += (size_t)512 * 512 * 2;
  unsigned short* Wkb = (unsigned short*)(ws + off); off += (size_t)512 * 512 * 2;
  unsigned short* bqb = (unsigned short*)(ws + off); off += 1024;
  unsigned short* bkb = (unsigned short*)(ws + off); off += 1024;
  unsigned short* Vt  = (unsigned short*)(ws + off); off += SZ_MAT;
  unsigned short* Qp  = (unsigned short*)(ws + off); off += SZ_MAT;
  unsigned short* Kp  = (unsigned short*)(ws + off); off += SZ_MAT;
  unsigned long long* mbits = (unsigned long long*)(ws + off); off += (size_t)8192 * 128 * 8;
  unsigned short* Opart = (unsigned short*)(ws + off); off += (size_t)256 * 32 * 8 * 64 * 8;  // 32 MB
  float* mpart = (float*)(ws + off); off += (size_t)4 * 8192 * 4;
  float* lpart = (float*)(ws + off); off += (size_t)4 * 8192 * 4;
  int* fflag = (int*)ws;
  int* esize = (int*)(ws + 64);

  k_detect<<<2, 64, 0, stream>>>((const unsigned int*)Q, (const unsigned int*)mask, fflag, esize);
  k_prep<<<4354, 256, 0, stream>>>(Q, Qb, K, Kb, WQw, Wqb, WKw, Wkb, WQb, bqb, WKb, bkb, fflag);
  k_transpose_v<<<dim3(128, 8), 256, 0, stream>>>(V, fflag, Vt);
  k_pack<<<1024, 256, 0, stream>>>(mask, esize, mbits);
  k_proj<<<dim3(64, 4, 2), 256, 0, stream>>>(Qb, Wqb, bqb, Qp, Kb, Wkb, bkb, Kp);
  k_attn<<<256, 512, 0, stream>>>(Qp, Kp, Vt, mbits, Opart, mpart, lpart);
  k_combine<<<dim3(64, 4), 512, 0, stream>>>(Opart, mpart, lpart, out);
}